// Round 1
// baseline (1613.568 us; speedup 1.0000x reference)
//
#include <hip/hip_runtime.h>
#include <hip/hip_bf16.h>
#include <math.h>

#define BATCH 2
#define CDIM 192
#define HH 56
#define WW 56
#define LSEQ 3136      // HH*WW
#define BL 6272        // BATCH*LSEQ
#define DIN 384
#define DST 16
#define DTR 12
#define XD 44          // DTR + 2*DST
#define MLPH 768
#define GH 48
#define NC 64          // scan chunks per sequence
#define CSZ 49         // chunk size; NC*CSZ == LSEQ

__device__ __forceinline__ float sigf(float x){ return 1.f/(1.f+__expf(-x)); }
__device__ __forceinline__ float siluf(float x){ return x*sigf(x); }

// ---------------- rmsnorm from NCHW: emits token-major x_tok and normed x_norm ----------------
__global__ void k_rmsnorm1(const float* __restrict__ x, const float* __restrict__ w,
                           float* __restrict__ x_tok, float* __restrict__ x_norm) {
  int t = blockIdx.x*blockDim.x + threadIdx.x;
  if (t >= BL) return;
  int b = t / LSEQ, l = t - b*LSEQ;
  const float* src = x + (size_t)b*CDIM*LSEQ + l;   // x[b][c][l], stride LSEQ over c
  float ss = 0.f;
  for (int c = 0; c < CDIM; ++c) { float v = src[(size_t)c*LSEQ]; ss += v*v; }
  float sc = rsqrtf(ss*(1.f/CDIM) + 1e-6f);
  float* o1 = x_tok  + (size_t)t*CDIM;
  float* o2 = x_norm + (size_t)t*CDIM;
  for (int c = 0; c < CDIM; ++c) { float v = src[(size_t)c*LSEQ]; o1[c] = v; o2[c] = v*sc*w[c]; }
}

// ---------------- rmsnorm on token-major input ----------------
__global__ void k_rmsnorm2(const float* __restrict__ in, const float* __restrict__ w,
                           float* __restrict__ out) {
  int t = blockIdx.x*blockDim.x + threadIdx.x;
  if (t >= BL) return;
  const float* src = in + (size_t)t*CDIM;
  float ss = 0.f;
  for (int c = 0; c < CDIM; ++c) { float v = src[c]; ss += v*v; }
  float sc = rsqrtf(ss*(1.f/CDIM) + 1e-6f);
  float* o = out + (size_t)t*CDIM;
  for (int c = 0; c < CDIM; ++c) o[c] = src[c]*sc*w[c];
}

// ---------------- GEMM: C[m][n] = act( A[maprow(m)][:K] . W[n][:K] + bias[n] ) ----------------
// A row-gather (rowmap=1) maps v-order tokens onto h-order x_norm rows.
__device__ __forceinline__ int maprow(int m, int rowmap) {
  if (rowmap == 0) return m;
  int b = m / LSEQ, lv = m - b*LSEQ;
  int h = lv % HH, w = lv / HH;     // lv = w*HH + h
  return b*LSEQ + h*WW + w;
}

__device__ __forceinline__ float apply_act(float v, int act) {
  if (act == 1) return 0.5f*v*(1.f+erff(v*0.70710678118654752f));   // exact gelu
  if (act == 2) return (v > 20.f) ? v : log1pf(__expf(v));          // softplus
  return v;
}

__global__ __launch_bounds__(256) void k_gemm(
    const float* __restrict__ A, int lda, int rowmap,
    const float* __restrict__ W, const float* __restrict__ bias,
    float* __restrict__ Cm, int ldc, int N, int K, int act) {
  __shared__ __align__(16) float As[8][132];
  __shared__ __align__(16) float Bs[8][132];
  int tid = threadIdx.x;
  int bm = blockIdx.x * 128, bn = blockIdx.y * 128;
  int tx = tid & 15, ty = tid >> 4;
  int tx8 = tx*8, ty8 = ty*8;
  float acc[8][8];
  #pragma unroll
  for (int i = 0; i < 8; ++i)
    #pragma unroll
    for (int j = 0; j < 8; ++j) acc[i][j] = 0.f;

  for (int k0 = 0; k0 < K; k0 += 8) {
    if (k0 + 8 <= K) {   // fully in-range K-tile: vectorized staging
      int r = tid >> 1, half = tid & 1, kb = half*4;
      int arow = maprow(bm + r, rowmap);
      float4 av = *(const float4*)(A + (size_t)arow*lda + k0 + half*4);
      As[kb+0][r]=av.x; As[kb+1][r]=av.y; As[kb+2][r]=av.z; As[kb+3][r]=av.w;
      int wrow = bn + r;
      float4 wv = make_float4(0.f,0.f,0.f,0.f);
      if (wrow < N) wv = *(const float4*)(W + (size_t)wrow*K + k0 + half*4);
      Bs[kb+0][r]=wv.x; Bs[kb+1][r]=wv.y; Bs[kb+2][r]=wv.z; Bs[kb+3][r]=wv.w;
    } else {             // ragged tail (K=44, K=12): masked scalar staging
      for (int i = tid; i < 1024; i += 256) {
        int r = i >> 3, kk = i & 7, kg = k0 + kk;
        int arow = maprow(bm + r, rowmap);
        As[kk][r] = (kg < K) ? A[(size_t)arow*lda + kg] : 0.f;
        int wrow = bn + r;
        Bs[kk][r] = (kg < K && wrow < N) ? W[(size_t)wrow*K + kg] : 0.f;
      }
    }
    __syncthreads();
    #pragma unroll
    for (int kk = 0; kk < 8; ++kk) {
      float a[8], bb[8];
      *(float4*)&a[0]  = *(const float4*)&As[kk][ty8];
      *(float4*)&a[4]  = *(const float4*)&As[kk][ty8+4];
      *(float4*)&bb[0] = *(const float4*)&Bs[kk][tx8];
      *(float4*)&bb[4] = *(const float4*)&Bs[kk][tx8+4];
      #pragma unroll
      for (int i = 0; i < 8; ++i)
        #pragma unroll
        for (int j = 0; j < 8; ++j) acc[i][j] = fmaf(a[i], bb[j], acc[i][j]);
    }
    __syncthreads();
  }

  #pragma unroll
  for (int i = 0; i < 8; ++i) {
    int m = bm + ty8 + i;
    float* crow = Cm + (size_t)m*ldc;
    #pragma unroll
    for (int j = 0; j < 8; ++j) {
      int n = bn + tx8 + j;
      if (n < N) {
        float v = acc[i][j] + (bias ? bias[n] : 0.f);
        crow[n] = apply_act(v, act);
      }
    }
  }
}

// ---------------- depthwise causal conv (dir 0) / anti-causal (dir 1) + silu ----------------
__global__ void k_conv(const float* __restrict__ xz, const float* __restrict__ cw,
                       const float* __restrict__ cb, int dir, float* __restrict__ u) {
  int i = blockIdx.x*256 + threadIdx.x;
  if (i >= BL*DIN) return;
  int d = i % DIN, t = i / DIN;
  int b = t / LSEQ, l = t - b*LSEQ;
  (void)b;
  float s = cb[d];
  const float* base = xz + (size_t)t*768 + d;    // xc part: cols [0,384)
  if (dir == 0) {
    if (l >= 3) s = fmaf(base[-3*768], cw[d*4+0], s);
    if (l >= 2) s = fmaf(base[-2*768], cw[d*4+1], s);
    if (l >= 1) s = fmaf(base[-1*768], cw[d*4+2], s);
    s = fmaf(base[0], cw[d*4+3], s);
  } else {
    if (l+3 < LSEQ) s = fmaf(base[3*768], cw[d*4+0], s);
    if (l+2 < LSEQ) s = fmaf(base[2*768], cw[d*4+1], s);
    if (l+1 < LSEQ) s = fmaf(base[1*768], cw[d*4+2], s);
    s = fmaf(base[0], cw[d*4+3], s);
  }
  u[i] = s*sigf(s);
}

// ---------------- chunked scan: pass A (local scan from 0 + chunk decay) ----------------
__global__ __launch_bounds__(384) void k_scanA(
    const float* __restrict__ u, const float* __restrict__ delta,
    const float* __restrict__ xdbl, const float* __restrict__ Alog,
    int dir, float* __restrict__ P, float* __restrict__ Hloc) {
  int c = blockIdx.x & (NC-1);
  int b = blockIdx.x >> 6;           // NC == 64
  int d = threadIdx.x;
  float An[DST], h[DST];
  #pragma unroll
  for (int n = 0; n < DST; ++n) { An[n] = -__expf(Alog[d*DST+n]); h[n] = 0.f; }
  float S = 0.f;
  int j0 = c*CSZ;
  for (int j = 0; j < CSZ; ++j) {
    int p = j0 + j;
    int l = dir ? (LSEQ-1-p) : p;
    size_t row = (size_t)b*LSEQ + l;
    float dlt = delta[row*DIN + d];
    float uu  = u[row*DIN + d];
    const float* xr = xdbl + row*XD;
    float du = dlt*uu;
    S += dlt;
    #pragma unroll
    for (int n = 0; n < DST; ++n) {
      float e = __expf(dlt*An[n]);
      h[n] = fmaf(e, h[n], du*xr[DTR+n]);
    }
  }
  size_t base = ((size_t)(b*DIN + d)*DST)*NC + c;
  #pragma unroll
  for (int n = 0; n < DST; ++n) {
    P[base + (size_t)n*NC]    = __expf(An[n]*S);   // prod of dA over chunk, closed form
    Hloc[base + (size_t)n*NC] = h[n];
  }
}

// ---------------- pass B: sequential chunk combine (64 steps per (b,d,n)) ----------------
__global__ void k_scanB(const float* __restrict__ P, const float* __restrict__ Hloc,
                        float* __restrict__ h0) {
  int i = blockIdx.x*256 + threadIdx.x;
  if (i >= BATCH*DIN*DST) return;
  const float* p  = P    + (size_t)i*NC;
  const float* hl = Hloc + (size_t)i*NC;
  float* o        = h0   + (size_t)i*NC;
  float carry = 0.f;
  for (int c = 0; c < NC; ++c) { o[c] = carry; carry = fmaf(p[c], carry, hl[c]); }
}

// ---------------- pass C: seeded scan producing y (+ u*D), writes at original token idx ----------------
__global__ __launch_bounds__(384) void k_scanC(
    const float* __restrict__ u, const float* __restrict__ delta,
    const float* __restrict__ xdbl, const float* __restrict__ h0,
    const float* __restrict__ Alog, const float* __restrict__ Dp,
    int dir, int accum, float* __restrict__ ysum) {
  int c = blockIdx.x & (NC-1);
  int b = blockIdx.x >> 6;
  int d = threadIdx.x;
  float An[DST], h[DST];
  size_t hb = ((size_t)(b*DIN + d)*DST)*NC + c;
  #pragma unroll
  for (int n = 0; n < DST; ++n) {
    An[n] = -__expf(Alog[d*DST+n]);
    h[n]  = h0[hb + (size_t)n*NC];
  }
  float Dd = Dp[d];
  int j0 = c*CSZ;
  for (int j = 0; j < CSZ; ++j) {
    int p = j0 + j;
    int l = dir ? (LSEQ-1-p) : p;
    size_t row = (size_t)b*LSEQ + l;
    float dlt = delta[row*DIN + d];
    float uu  = u[row*DIN + d];
    const float* xr = xdbl + row*XD;
    float du = dlt*uu;
    float y = 0.f;
    #pragma unroll
    for (int n = 0; n < DST; ++n) {
      float e = __expf(dlt*An[n]);
      h[n] = fmaf(e, h[n], du*xr[DTR+n]);
      y = fmaf(h[n], xr[DTR+DST+n], y);
    }
    y = fmaf(uu, Dd, y);
    size_t oi = row*DIN + d;
    if (accum) ysum[oi] += y; else ysum[oi] = y;
  }
}

// ---------------- y *= silu(z) ----------------
__global__ void k_yfinal(float* __restrict__ ysum, const float* __restrict__ xz) {
  int i = blockIdx.x*256 + threadIdx.x;
  if (i >= BL*DIN) return;
  int t = i / DIN, d = i - t*DIN;
  float z = xz[(size_t)t*768 + DIN + d];
  ysum[i] *= siluf(z);
}

// ---------------- ctx partial sums: part[b][chunk][c] = sum_{64 tokens} (out_h + out_v) ----------------
__global__ void k_ctxpart(const float* __restrict__ out_h, const float* __restrict__ out_v,
                          float* __restrict__ part) {
  int blk = blockIdx.x;            // BATCH*49
  int b = blk / 49, ch = blk % 49;
  int c = threadIdx.x;             // 192
  int t0 = b*LSEQ + ch*64;
  float s = 0.f;
  for (int k = 0; k < 64; ++k) {
    size_t idx = (size_t)(t0 + k)*CDIM + c;
    s += out_h[idx] + out_v[idx];
  }
  part[(size_t)blk*CDIM + c] = s;
}

// ---------------- gate MLP (single block) ----------------
__global__ void k_gate(const float* __restrict__ part,
                       const float* __restrict__ w1, const float* __restrict__ b1,
                       const float* __restrict__ w2, const float* __restrict__ b2,
                       float* __restrict__ gate) {
  __shared__ float ctxs[BATCH][CDIM];
  __shared__ float hid[BATCH][GH];
  int t = threadIdx.x;             // 256
  for (int idx = t; idx < BATCH*CDIM; idx += 256) {
    int b = idx / CDIM, c = idx % CDIM;
    float s = 0.f;
    for (int k = 0; k < 49; ++k) s += part[(size_t)(b*49+k)*CDIM + c];
    ctxs[b][c] = s * (0.5f/(float)LSEQ);
  }
  __syncthreads();
  if (t < BATCH*GH) {
    int b = t / GH, g = t % GH;
    float s = b1[g];
    for (int c = 0; c < CDIM; ++c) s = fmaf(ctxs[b][c], w1[g*CDIM+c], s);
    hid[b][g] = fmaxf(s, 0.f);
  }
  __syncthreads();
  for (int idx = t; idx < BATCH*CDIM; idx += 256) {
    int b = idx / CDIM, c = idx % CDIM;
    float s = b2[c];
    for (int g = 0; g < GH; ++g) s = fmaf(hid[b][g], w2[c*GH+g], s);
    gate[idx] = sigf(s);
  }
}

// ---------------- fuse: x2 = x_tok + g*out_h + (1-g)*out_v(v-order gather) ----------------
__global__ void k_fuse(const float* __restrict__ x_tok, const float* __restrict__ out_h,
                       const float* __restrict__ out_v, const float* __restrict__ gate,
                       float* __restrict__ x2) {
  int i = blockIdx.x*256 + threadIdx.x;
  if (i >= BL*CDIM) return;
  int c = i % CDIM;
  int t = i / CDIM;
  int b = t / LSEQ, l = t - b*LSEQ;
  int h = l / WW, w = l - h*WW;
  int lv = w*HH + h;
  float g = gate[b*CDIM + c];
  float ov = out_v[((size_t)(b*LSEQ + lv))*CDIM + c];
  x2[i] = x_tok[i] + g*out_h[i] + (1.f-g)*ov;
}

// ---------------- final: out[b][c][h][w] = x2 + t2 (token-major gather) ----------------
__global__ void k_final(const float* __restrict__ x2, const float* __restrict__ t2,
                        float* __restrict__ out) {
  int i = blockIdx.x*256 + threadIdx.x;
  if (i >= BL*CDIM) return;
  int l = i % LSEQ;
  int bc = i / LSEQ;
  int c = bc % CDIM, b = bc / CDIM;
  size_t src = ((size_t)(b*LSEQ + l))*CDIM + c;
  out[i] = x2[src] + t2[src];
}

static inline void gemm(const float* A, int lda, int rowmap, const float* W,
                        const float* bias, float* Cm, int ldc, int N, int K, int act,
                        hipStream_t s) {
  dim3 g(BL/128, (N+127)/128);
  k_gemm<<<g, 256, 0, s>>>(A, lda, rowmap, W, bias, Cm, ldc, N, K, act);
}

extern "C" void kernel_launch(void* const* d_in, const int* in_sizes, int n_in,
                              void* d_out, int out_size, void* d_ws, size_t ws_size,
                              hipStream_t stream) {
  (void)in_sizes; (void)n_in; (void)out_size; (void)ws_size;
  const float* x   = (const float*)d_in[0];
  const float* n1w = (const float*)d_in[1];
  const float* n2w = (const float*)d_in[2];
  const float* in_w[2]   = {(const float*)d_in[3],  (const float*)d_in[12]};
  const float* conv_w[2] = {(const float*)d_in[4],  (const float*)d_in[13]};
  const float* conv_b[2] = {(const float*)d_in[5],  (const float*)d_in[14]};
  const float* xp_w[2]   = {(const float*)d_in[6],  (const float*)d_in[15]};
  const float* dt_w[2]   = {(const float*)d_in[7],  (const float*)d_in[16]};
  const float* dt_b[2]   = {(const float*)d_in[8],  (const float*)d_in[17]};
  const float* Alog[2]   = {(const float*)d_in[9],  (const float*)d_in[18]};
  const float* Dp[2]     = {(const float*)d_in[10], (const float*)d_in[19]};
  const float* out_w[2]  = {(const float*)d_in[11], (const float*)d_in[20]};
  const float* gw1 = (const float*)d_in[21];
  const float* gb1 = (const float*)d_in[22];
  const float* gw2 = (const float*)d_in[23];
  const float* gb2 = (const float*)d_in[24];
  const float* mw1 = (const float*)d_in[25];
  const float* mb1 = (const float*)d_in[26];
  const float* mw2 = (const float*)d_in[27];
  const float* mb2 = (const float*)d_in[28];

  float* ws = (float*)d_ws;
  float* x_tok  = ws;  ws += 1204224;              // [BL,192]
  float* x_norm = ws;  ws += 1204224;              // later: x_tok2
  float* out_o0 = ws;  ws += 1204224;              // out_h (h-order)
  float* out_o1 = ws;  ws += 1204224;              // out_v (v-order)
  float* xz     = ws;  ws += 4816896;              // [BL,768]; later: t1
  float* ubuf   = ws;  ws += 2408448;              // [BL,384]; later: t2
  float* dbuf   = ws;  ws += 2408448;              // delta
  float* xdbl   = ws;  ws += 275968;               // [BL,44]
  float* ysum   = ws;  ws += 2408448;
  float* Pb     = ws;  ws += 786432;               // [B,DIN,DST,NC]
  float* Hl     = ws;  ws += 786432;
  float* h0b    = ws;  ws += 786432;
  float* part   = ws;  ws += 18816;                // [B,49,192]
  float* gateb  = ws;  ws += 384;
  float* out_o[2] = {out_o0, out_o1};
  float* x2  = x_norm;   // aliases (lifetimes disjoint)
  float* xn2 = x_tok;
  float* t1  = xz;
  float* t2  = ubuf;
  float* out = (float*)d_out;

  k_rmsnorm1<<<(BL+255)/256, 256, 0, stream>>>(x, n1w, x_tok, x_norm);

  for (int o = 0; o < 2; ++o) {
    // shared in_proj per orientation (flip-invariant)
    gemm(x_norm, CDIM, o, in_w[o], nullptr, xz, 768, 768, CDIM, 0, stream);
    for (int dir = 0; dir < 2; ++dir) {
      k_conv<<<(BL*DIN+255)/256, 256, 0, stream>>>(xz, conv_w[o], conv_b[o], dir, ubuf);
      gemm(ubuf, DIN, 0, xp_w[o], nullptr, xdbl, XD, XD, DIN, 0, stream);
      gemm(xdbl, XD, 0, dt_w[o], dt_b[o], dbuf, DIN, DIN, DTR, 2, stream);   // softplus
      k_scanA<<<BATCH*NC, 384, 0, stream>>>(ubuf, dbuf, xdbl, Alog[o], dir, Pb, Hl);
      k_scanB<<<(BATCH*DIN*DST+255)/256, 256, 0, stream>>>(Pb, Hl, h0b);
      k_scanC<<<BATCH*NC, 384, 0, stream>>>(ubuf, dbuf, xdbl, h0b, Alog[o], Dp[o],
                                            dir, dir /*accum on bwd*/, ysum);
    }
    k_yfinal<<<(BL*DIN+255)/256, 256, 0, stream>>>(ysum, xz);
    // shared out_proj per orientation (distributes over fwd+bwd sum)
    gemm(ysum, DIN, 0, out_w[o], nullptr, out_o[o], CDIM, CDIM, DIN, 0, stream);
  }

  k_ctxpart<<<BATCH*49, CDIM, 0, stream>>>(out_o0, out_o1, part);
  k_gate<<<1, 256, 0, stream>>>(part, gw1, gb1, gw2, gb2, gateb);
  k_fuse<<<(BL*CDIM+255)/256, 256, 0, stream>>>(x_tok, out_o0, out_o1, gateb, x2);
  k_rmsnorm2<<<(BL+255)/256, 256, 0, stream>>>(x2, n2w, xn2);
  gemm(xn2, CDIM, 0, mw1, mb1, t1, MLPH, MLPH, CDIM, 1, stream);    // gelu
  gemm(t1, MLPH, 0, mw2, mb2, t2, CDIM, CDIM, MLPH, 0, stream);
  k_final<<<(BL*CDIM+255)/256, 256, 0, stream>>>(x2, t2, out);
}

// Round 2
// 940.607 us; speedup vs baseline: 1.7155x; 1.7155x over previous
//
#include <hip/hip_runtime.h>
#include <hip/hip_bf16.h>
#include <math.h>

#define BATCH 2
#define CDIM 192
#define HH 56
#define WW 56
#define LSEQ 3136      // HH*WW
#define BL 6272        // BATCH*LSEQ
#define DIN 384
#define DST 16
#define DTR 12
#define XD 44          // DTR + 2*DST
#define MLPH 768
#define GH 48
#define NC 64          // scan chunks per sequence
#define CSZ 49         // chunk size; NC*CSZ == LSEQ

__device__ __forceinline__ float sigf(float x){ return 1.f/(1.f+__expf(-x)); }
__device__ __forceinline__ float siluf(float x){ return x*sigf(x); }

// ---------------- rmsnorm from NCHW: emits token-major x_tok and normed x_norm ----------------
__global__ void k_rmsnorm1(const float* __restrict__ x, const float* __restrict__ w,
                           float* __restrict__ x_tok, float* __restrict__ x_norm) {
  int t = blockIdx.x*blockDim.x + threadIdx.x;
  if (t >= BL) return;
  int b = t / LSEQ, l = t - b*LSEQ;
  const float* src = x + (size_t)b*CDIM*LSEQ + l;   // x[b][c][l], stride LSEQ over c
  float ss = 0.f;
  for (int c = 0; c < CDIM; ++c) { float v = src[(size_t)c*LSEQ]; ss += v*v; }
  float sc = rsqrtf(ss*(1.f/CDIM) + 1e-6f);
  float* o1 = x_tok  + (size_t)t*CDIM;
  float* o2 = x_norm + (size_t)t*CDIM;
  for (int c = 0; c < CDIM; ++c) { float v = src[(size_t)c*LSEQ]; o1[c] = v; o2[c] = v*sc*w[c]; }
}

// ---------------- rmsnorm on token-major input ----------------
__global__ void k_rmsnorm2(const float* __restrict__ in, const float* __restrict__ w,
                           float* __restrict__ out) {
  int t = blockIdx.x*blockDim.x + threadIdx.x;
  if (t >= BL) return;
  const float* src = in + (size_t)t*CDIM;
  float ss = 0.f;
  for (int c = 0; c < CDIM; ++c) { float v = src[c]; ss += v*v; }
  float sc = rsqrtf(ss*(1.f/CDIM) + 1e-6f);
  float* o = out + (size_t)t*CDIM;
  for (int c = 0; c < CDIM; ++c) o[c] = src[c]*sc*w[c];
}

// ---------------- GEMM: C[m][n] = act( A[maprow(m)][:K] . W[n][:K] + bias[n] ) ----------------
// A row-gather (rowmap=1) maps v-order tokens onto h-order x_norm rows.
__device__ __forceinline__ int maprow(int m, int rowmap) {
  if (rowmap == 0) return m;
  int b = m / LSEQ, lv = m - b*LSEQ;
  int h = lv % HH, w = lv / HH;     // lv = w*HH + h
  return b*LSEQ + h*WW + w;
}

__device__ __forceinline__ float apply_act(float v, int act) {
  if (act == 1) return 0.5f*v*(1.f+erff(v*0.70710678118654752f));   // exact gelu
  if (act == 2) return (v > 20.f) ? v : log1pf(__expf(v));          // softplus
  return v;
}

// 64x64 tile, 256 threads, 4x4 microtile, KT=16.
// Grid 4x larger than 128-tile version -> fixes the 4.3% occupancy.
__global__ __launch_bounds__(256) void k_gemm(
    const float* __restrict__ A, int lda, int rowmap,
    const float* __restrict__ W, const float* __restrict__ bias,
    float* __restrict__ Cm, int ldc, int N, int K, int act) {
  __shared__ __align__(16) float As[16][68];
  __shared__ __align__(16) float Bs[16][68];
  int tid = threadIdx.x;
  int bm = blockIdx.x * 64, bn = blockIdx.y * 64;
  int tx = tid & 15, ty = tid >> 4;
  int tx4 = tx*4, ty4 = ty*4;
  float acc[4][4];
  #pragma unroll
  for (int i = 0; i < 4; ++i)
    #pragma unroll
    for (int j = 0; j < 4; ++j) acc[i][j] = 0.f;

  // staging: thread loads float4 of row r at k-offset kq
  int r  = tid >> 2;          // 0..63
  int kq = (tid & 3) * 4;     // 0,4,8,12
  int arow = maprow(bm + r, rowmap);          // M=6272 always divisible by 64
  const float* Arow = A + (size_t)arow*lda;
  int wrow = bn + r;
  const float* Wrow = W + (size_t)wrow*K;
  bool wok = wrow < N;

  for (int k0 = 0; k0 < K; k0 += 16) {
    if (k0 + 16 <= K) {       // in-range: vectorized staging
      float4 av = *(const float4*)(Arow + k0 + kq);
      As[kq+0][r]=av.x; As[kq+1][r]=av.y; As[kq+2][r]=av.z; As[kq+3][r]=av.w;
      float4 wv = make_float4(0.f,0.f,0.f,0.f);
      if (wok) wv = *(const float4*)(Wrow + k0 + kq);
      Bs[kq+0][r]=wv.x; Bs[kq+1][r]=wv.y; Bs[kq+2][r]=wv.z; Bs[kq+3][r]=wv.w;
    } else {                  // ragged tail (K=44 -> 12, K=12): masked scalar, zero-pad
      #pragma unroll
      for (int j = 0; j < 4; ++j) {
        int kg = k0 + kq + j;
        As[kq+j][r] = (kg < K) ? Arow[kg] : 0.f;
        Bs[kq+j][r] = (kg < K && wok) ? Wrow[kg] : 0.f;
      }
    }
    __syncthreads();
    #pragma unroll
    for (int kk = 0; kk < 16; ++kk) {
      float4 a = *(const float4*)&As[kk][ty4];
      float4 b = *(const float4*)&Bs[kk][tx4];
      float av4[4] = {a.x, a.y, a.z, a.w};
      float bv4[4] = {b.x, b.y, b.z, b.w};
      #pragma unroll
      for (int i = 0; i < 4; ++i)
        #pragma unroll
        for (int j = 0; j < 4; ++j) acc[i][j] = fmaf(av4[i], bv4[j], acc[i][j]);
    }
    __syncthreads();
  }

  #pragma unroll
  for (int i = 0; i < 4; ++i) {
    int m = bm + ty4 + i;
    float* crow = Cm + (size_t)m*ldc;
    #pragma unroll
    for (int j = 0; j < 4; ++j) {
      int n = bn + tx4 + j;
      if (n < N) {
        float v = acc[i][j] + (bias ? bias[n] : 0.f);
        crow[n] = apply_act(v, act);
      }
    }
  }
}

// ---------------- depthwise causal conv (dir 0) / anti-causal (dir 1) + silu ----------------
__global__ void k_conv(const float* __restrict__ xz, const float* __restrict__ cw,
                       const float* __restrict__ cb, int dir, float* __restrict__ u) {
  int i = blockIdx.x*256 + threadIdx.x;
  if (i >= BL*DIN) return;
  int d = i % DIN, t = i / DIN;
  int b = t / LSEQ, l = t - b*LSEQ;
  (void)b;
  float s = cb[d];
  const float* base = xz + (size_t)t*768 + d;    // xc part: cols [0,384)
  if (dir == 0) {
    if (l >= 3) s = fmaf(base[-3*768], cw[d*4+0], s);
    if (l >= 2) s = fmaf(base[-2*768], cw[d*4+1], s);
    if (l >= 1) s = fmaf(base[-1*768], cw[d*4+2], s);
    s = fmaf(base[0], cw[d*4+3], s);
  } else {
    if (l+3 < LSEQ) s = fmaf(base[3*768], cw[d*4+0], s);
    if (l+2 < LSEQ) s = fmaf(base[2*768], cw[d*4+1], s);
    if (l+1 < LSEQ) s = fmaf(base[1*768], cw[d*4+2], s);
    s = fmaf(base[0], cw[d*4+3], s);
  }
  u[i] = s*sigf(s);
}

// ---------------- chunked scan: pass A (local scan from 0 + chunk decay) ----------------
__global__ __launch_bounds__(384) void k_scanA(
    const float* __restrict__ u, const float* __restrict__ delta,
    const float* __restrict__ xdbl, const float* __restrict__ Alog,
    int dir, float* __restrict__ P, float* __restrict__ Hloc) {
  int c = blockIdx.x & (NC-1);
  int b = blockIdx.x >> 6;           // NC == 64
  int d = threadIdx.x;
  float An[DST], h[DST];
  #pragma unroll
  for (int n = 0; n < DST; ++n) { An[n] = -__expf(Alog[d*DST+n]); h[n] = 0.f; }
  float S = 0.f;
  int j0 = c*CSZ;
  for (int j = 0; j < CSZ; ++j) {
    int p = j0 + j;
    int l = dir ? (LSEQ-1-p) : p;
    size_t row = (size_t)b*LSEQ + l;
    float dlt = delta[row*DIN + d];
    float uu  = u[row*DIN + d];
    const float* xr = xdbl + row*XD;
    float du = dlt*uu;
    S += dlt;
    #pragma unroll
    for (int n = 0; n < DST; ++n) {
      float e = __expf(dlt*An[n]);
      h[n] = fmaf(e, h[n], du*xr[DTR+n]);
    }
  }
  size_t base = ((size_t)(b*DIN + d)*DST)*NC + c;
  #pragma unroll
  for (int n = 0; n < DST; ++n) {
    P[base + (size_t)n*NC]    = __expf(An[n]*S);   // prod of dA over chunk, closed form
    Hloc[base + (size_t)n*NC] = h[n];
  }
}

// ---------------- pass B: sequential chunk combine (64 steps per (b,d,n)) ----------------
__global__ void k_scanB(const float* __restrict__ P, const float* __restrict__ Hloc,
                        float* __restrict__ h0) {
  int i = blockIdx.x*256 + threadIdx.x;
  if (i >= BATCH*DIN*DST) return;
  const float* p  = P    + (size_t)i*NC;
  const float* hl = Hloc + (size_t)i*NC;
  float* o        = h0   + (size_t)i*NC;
  float carry = 0.f;
  for (int c = 0; c < NC; ++c) { o[c] = carry; carry = fmaf(p[c], carry, hl[c]); }
}

// ---------------- pass C: seeded scan producing y (+ u*D), writes at original token idx ----------------
__global__ __launch_bounds__(384) void k_scanC(
    const float* __restrict__ u, const float* __restrict__ delta,
    const float* __restrict__ xdbl, const float* __restrict__ h0,
    const float* __restrict__ Alog, const float* __restrict__ Dp,
    int dir, int accum, float* __restrict__ ysum) {
  int c = blockIdx.x & (NC-1);
  int b = blockIdx.x >> 6;
  int d = threadIdx.x;
  float An[DST], h[DST];
  size_t hb = ((size_t)(b*DIN + d)*DST)*NC + c;
  #pragma unroll
  for (int n = 0; n < DST; ++n) {
    An[n] = -__expf(Alog[d*DST+n]);
    h[n]  = h0[hb + (size_t)n*NC];
  }
  float Dd = Dp[d];
  int j0 = c*CSZ;
  for (int j = 0; j < CSZ; ++j) {
    int p = j0 + j;
    int l = dir ? (LSEQ-1-p) : p;
    size_t row = (size_t)b*LSEQ + l;
    float dlt = delta[row*DIN + d];
    float uu  = u[row*DIN + d];
    const float* xr = xdbl + row*XD;
    float du = dlt*uu;
    float y = 0.f;
    #pragma unroll
    for (int n = 0; n < DST; ++n) {
      float e = __expf(dlt*An[n]);
      h[n] = fmaf(e, h[n], du*xr[DTR+n]);
      y = fmaf(h[n], xr[DTR+DST+n], y);
    }
    y = fmaf(uu, Dd, y);
    size_t oi = row*DIN + d;
    if (accum) ysum[oi] += y; else ysum[oi] = y;
  }
}

// ---------------- y *= silu(z) ----------------
__global__ void k_yfinal(float* __restrict__ ysum, const float* __restrict__ xz) {
  int i = blockIdx.x*256 + threadIdx.x;
  if (i >= BL*DIN) return;
  int t = i / DIN, d = i - t*DIN;
  float z = xz[(size_t)t*768 + DIN + d];
  ysum[i] *= siluf(z);
}

// ---------------- ctx partial sums: part[b][chunk][c] = sum_{64 tokens} (out_h + out_v) ----------------
__global__ void k_ctxpart(const float* __restrict__ out_h, const float* __restrict__ out_v,
                          float* __restrict__ part) {
  int blk = blockIdx.x;            // BATCH*49
  int b = blk / 49, ch = blk % 49;
  int c = threadIdx.x;             // 192
  int t0 = b*LSEQ + ch*64;
  float s = 0.f;
  for (int k = 0; k < 64; ++k) {
    size_t idx = (size_t)(t0 + k)*CDIM + c;
    s += out_h[idx] + out_v[idx];
  }
  part[(size_t)blk*CDIM + c] = s;
}

// ---------------- gate MLP (single block) ----------------
__global__ void k_gate(const float* __restrict__ part,
                       const float* __restrict__ w1, const float* __restrict__ b1,
                       const float* __restrict__ w2, const float* __restrict__ b2,
                       float* __restrict__ gate) {
  __shared__ float ctxs[BATCH][CDIM];
  __shared__ float hid[BATCH][GH];
  int t = threadIdx.x;             // 256
  for (int idx = t; idx < BATCH*CDIM; idx += 256) {
    int b = idx / CDIM, c = idx % CDIM;
    float s = 0.f;
    for (int k = 0; k < 49; ++k) s += part[(size_t)(b*49+k)*CDIM + c];
    ctxs[b][c] = s * (0.5f/(float)LSEQ);
  }
  __syncthreads();
  if (t < BATCH*GH) {
    int b = t / GH, g = t % GH;
    float s = b1[g];
    for (int c = 0; c < CDIM; ++c) s = fmaf(ctxs[b][c], w1[g*CDIM+c], s);
    hid[b][g] = fmaxf(s, 0.f);
  }
  __syncthreads();
  for (int idx = t; idx < BATCH*CDIM; idx += 256) {
    int b = idx / CDIM, c = idx % CDIM;
    float s = b2[c];
    for (int g = 0; g < GH; ++g) s = fmaf(hid[b][g], w2[c*GH+g], s);
    gate[idx] = sigf(s);
  }
}

// ---------------- fuse: x2 = x_tok + g*out_h + (1-g)*out_v(v-order gather) ----------------
__global__ void k_fuse(const float* __restrict__ x_tok, const float* __restrict__ out_h,
                       const float* __restrict__ out_v, const float* __restrict__ gate,
                       float* __restrict__ x2) {
  int i = blockIdx.x*256 + threadIdx.x;
  if (i >= BL*CDIM) return;
  int c = i % CDIM;
  int t = i / CDIM;
  int b = t / LSEQ, l = t - b*LSEQ;
  int h = l / WW, w = l - h*WW;
  int lv = w*HH + h;
  float g = gate[b*CDIM + c];
  float ov = out_v[((size_t)(b*LSEQ + lv))*CDIM + c];
  x2[i] = x_tok[i] + g*out_h[i] + (1.f-g)*ov;
}

// ---------------- final: out[b][c][h][w] = x2 + t2 (token-major gather) ----------------
__global__ void k_final(const float* __restrict__ x2, const float* __restrict__ t2,
                        float* __restrict__ out) {
  int i = blockIdx.x*256 + threadIdx.x;
  if (i >= BL*CDIM) return;
  int l = i % LSEQ;
  int bc = i / LSEQ;
  int c = bc % CDIM, b = bc / CDIM;
  size_t src = ((size_t)(b*LSEQ + l))*CDIM + c;
  out[i] = x2[src] + t2[src];
}

static inline void gemm(const float* A, int lda, int rowmap, const float* W,
                        const float* bias, float* Cm, int ldc, int N, int K, int act,
                        hipStream_t s) {
  dim3 g(BL/64, (N+63)/64);
  k_gemm<<<g, 256, 0, s>>>(A, lda, rowmap, W, bias, Cm, ldc, N, K, act);
}

extern "C" void kernel_launch(void* const* d_in, const int* in_sizes, int n_in,
                              void* d_out, int out_size, void* d_ws, size_t ws_size,
                              hipStream_t stream) {
  (void)in_sizes; (void)n_in; (void)out_size; (void)ws_size;
  const float* x   = (const float*)d_in[0];
  const float* n1w = (const float*)d_in[1];
  const float* n2w = (const float*)d_in[2];
  const float* in_w[2]   = {(const float*)d_in[3],  (const float*)d_in[12]};
  const float* conv_w[2] = {(const float*)d_in[4],  (const float*)d_in[13]};
  const float* conv_b[2] = {(const float*)d_in[5],  (const float*)d_in[14]};
  const float* xp_w[2]   = {(const float*)d_in[6],  (const float*)d_in[15]};
  const float* dt_w[2]   = {(const float*)d_in[7],  (const float*)d_in[16]};
  const float* dt_b[2]   = {(const float*)d_in[8],  (const float*)d_in[17]};
  const float* Alog[2]   = {(const float*)d_in[9],  (const float*)d_in[18]};
  const float* Dp[2]     = {(const float*)d_in[10], (const float*)d_in[19]};
  const float* out_w[2]  = {(const float*)d_in[11], (const float*)d_in[20]};
  const float* gw1 = (const float*)d_in[21];
  const float* gb1 = (const float*)d_in[22];
  const float* gw2 = (const float*)d_in[23];
  const float* gb2 = (const float*)d_in[24];
  const float* mw1 = (const float*)d_in[25];
  const float* mb1 = (const float*)d_in[26];
  const float* mw2 = (const float*)d_in[27];
  const float* mb2 = (const float*)d_in[28];

  float* ws = (float*)d_ws;
  float* x_tok  = ws;  ws += 1204224;              // [BL,192]
  float* x_norm = ws;  ws += 1204224;              // later: x_tok2
  float* out_o0 = ws;  ws += 1204224;              // out_h (h-order)
  float* out_o1 = ws;  ws += 1204224;              // out_v (v-order)
  float* xz     = ws;  ws += 4816896;              // [BL,768]; later: t1
  float* ubuf   = ws;  ws += 2408448;              // [BL,384]; later: t2
  float* dbuf   = ws;  ws += 2408448;              // delta
  float* xdbl   = ws;  ws += 275968;               // [BL,44]
  float* ysum   = ws;  ws += 2408448;
  float* Pb     = ws;  ws += 786432;               // [B,DIN,DST,NC]
  float* Hl     = ws;  ws += 786432;
  float* h0b    = ws;  ws += 786432;
  float* part   = ws;  ws += 18816;                // [B,49,192]
  float* gateb  = ws;  ws += 384;
  float* out_o[2] = {out_o0, out_o1};
  float* x2  = x_norm;   // aliases (lifetimes disjoint)
  float* xn2 = x_tok;
  float* t1  = xz;
  float* t2  = ubuf;
  float* out = (float*)d_out;

  k_rmsnorm1<<<(BL+255)/256, 256, 0, stream>>>(x, n1w, x_tok, x_norm);

  for (int o = 0; o < 2; ++o) {
    // shared in_proj per orientation (flip-invariant)
    gemm(x_norm, CDIM, o, in_w[o], nullptr, xz, 768, 768, CDIM, 0, stream);
    for (int dir = 0; dir < 2; ++dir) {
      k_conv<<<(BL*DIN+255)/256, 256, 0, stream>>>(xz, conv_w[o], conv_b[o], dir, ubuf);
      gemm(ubuf, DIN, 0, xp_w[o], nullptr, xdbl, XD, XD, DIN, 0, stream);
      gemm(xdbl, XD, 0, dt_w[o], dt_b[o], dbuf, DIN, DIN, DTR, 2, stream);   // softplus
      k_scanA<<<BATCH*NC, 384, 0, stream>>>(ubuf, dbuf, xdbl, Alog[o], dir, Pb, Hl);
      k_scanB<<<(BATCH*DIN*DST+255)/256, 256, 0, stream>>>(Pb, Hl, h0b);
      k_scanC<<<BATCH*NC, 384, 0, stream>>>(ubuf, dbuf, xdbl, h0b, Alog[o], Dp[o],
                                            dir, dir /*accum on bwd*/, ysum);
    }
    k_yfinal<<<(BL*DIN+255)/256, 256, 0, stream>>>(ysum, xz);
    // shared out_proj per orientation (distributes over fwd+bwd sum)
    gemm(ysum, DIN, 0, out_w[o], nullptr, out_o[o], CDIM, CDIM, DIN, 0, stream);
  }

  k_ctxpart<<<BATCH*49, CDIM, 0, stream>>>(out_o0, out_o1, part);
  k_gate<<<1, 256, 0, stream>>>(part, gw1, gb1, gw2, gb2, gateb);
  k_fuse<<<(BL*CDIM+255)/256, 256, 0, stream>>>(x_tok, out_o0, out_o1, gateb, x2);
  k_rmsnorm2<<<(BL+255)/256, 256, 0, stream>>>(x2, n2w, xn2);
  gemm(xn2, CDIM, 0, mw1, mb1, t1, MLPH, MLPH, CDIM, 1, stream);    // gelu
  gemm(t1, MLPH, 0, mw2, mb2, t2, CDIM, CDIM, MLPH, 0, stream);
  k_final<<<(BL*CDIM+255)/256, 256, 0, stream>>>(x2, t2, out);
}

// Round 3
// 599.029 us; speedup vs baseline: 2.6936x; 1.5702x over previous
//
#include <hip/hip_runtime.h>
#include <hip/hip_bf16.h>
#include <math.h>

#define BATCH 2
#define CDIM 192
#define HH 56
#define WW 56
#define LSEQ 3136      // HH*WW
#define BL 6272        // BATCH*LSEQ
#define DIN 384
#define DST 16
#define DTR 12
#define XD 44          // DTR + 2*DST
#define MLPH 768
#define GH 48
#define NC 64          // scan chunks per sequence
#define CSZ 49         // chunk size; NC*CSZ == LSEQ

__device__ __forceinline__ float sigf(float x){ return 1.f/(1.f+__expf(-x)); }
__device__ __forceinline__ float siluf(float x){ return x*sigf(x); }

// ---------------- rmsnorm from NCHW: emits token-major x_tok and normed x_norm ----------------
__global__ void k_rmsnorm1(const float* __restrict__ x, const float* __restrict__ w,
                           float* __restrict__ x_tok, float* __restrict__ x_norm) {
  int t = blockIdx.x*blockDim.x + threadIdx.x;
  if (t >= BL) return;
  int b = t / LSEQ, l = t - b*LSEQ;
  const float* src = x + (size_t)b*CDIM*LSEQ + l;   // x[b][c][l], stride LSEQ over c
  float ss = 0.f;
  for (int c = 0; c < CDIM; ++c) { float v = src[(size_t)c*LSEQ]; ss += v*v; }
  float sc = rsqrtf(ss*(1.f/CDIM) + 1e-6f);
  float* o1 = x_tok  + (size_t)t*CDIM;
  float* o2 = x_norm + (size_t)t*CDIM;
  for (int c = 0; c < CDIM; ++c) { float v = src[(size_t)c*LSEQ]; o1[c] = v; o2[c] = v*sc*w[c]; }
}

// ---------------- rmsnorm on token-major input ----------------
__global__ void k_rmsnorm2(const float* __restrict__ in, const float* __restrict__ w,
                           float* __restrict__ out) {
  int t = blockIdx.x*blockDim.x + threadIdx.x;
  if (t >= BL) return;
  const float* src = in + (size_t)t*CDIM;
  float ss = 0.f;
  for (int c = 0; c < CDIM; ++c) { float v = src[c]; ss += v*v; }
  float sc = rsqrtf(ss*(1.f/CDIM) + 1e-6f);
  float* o = out + (size_t)t*CDIM;
  for (int c = 0; c < CDIM; ++c) o[c] = src[c]*sc*w[c];
}

// ---------------- batched GEMM ----------------
// rowmode 0: arow = m
// rowmode 1: in_proj batched: m in [0,2BL): o=m/BL, t=m%BL; o==0 -> t, o==1 -> v-order gather
// rowmode 2: out_proj batched: m in [0,2BL): arow = (m/BL)*2*BL + (m%BL)  (picks y4[q=0],y4[q=2])
__device__ __forceinline__ int arow_of(int m, int rowmode) {
  if (rowmode == 0) return m;
  int o = m / BL, t = m - o*BL;
  if (rowmode == 2) return o*2*BL + t;
  if (o == 0) return t;
  int b = t / LSEQ, lv = t - b*LSEQ;
  int h = lv % HH, w = lv / HH;     // lv = w*HH + h
  return b*LSEQ + h*WW + w;
}

__device__ __forceinline__ float apply_act(float v, int act) {
  if (act == 1) return 0.5f*v*(1.f+erff(v*0.70710678118654752f));   // exact gelu
  if (act == 2) return (v > 20.f) ? v : log1pf(__expf(v));          // softplus
  return v;
}

// TM x 64 tile, 256 threads, (TM/16)x4 microtile, KT=16.
// Weight/bias segment select: rows >= seg use W1/b1.
template<int TM>
__global__ __launch_bounds__(256) void k_gemm(
    const float* __restrict__ A, int lda, int rowmode,
    const float* __restrict__ W0, const float* __restrict__ W1,
    const float* __restrict__ b0, const float* __restrict__ b1, int seg,
    float* __restrict__ Cm, int ldc, int N, int K, int act) {
  constexpr int MR = TM/16;
  __shared__ __align__(16) float As[16][TM+4];
  __shared__ __align__(16) float Bs[16][68];
  int tid = threadIdx.x;
  int bm = blockIdx.x * TM, bn = blockIdx.y * 64;
  const float* W    = (bm >= seg) ? W1 : W0;
  const float* bias = (bm >= seg) ? b1 : b0;
  int tx = tid & 15, ty = tid >> 4;
  float acc[MR][4];
  #pragma unroll
  for (int i = 0; i < MR; ++i)
    #pragma unroll
    for (int j = 0; j < 4; ++j) acc[i][j] = 0.f;

  int ar, akq;
  if constexpr (TM == 64) { ar = tid >> 2; akq = (tid & 3) * 4; }
  else                    { ar = tid >> 3; akq = (tid & 7) * 2; }
  int arow = arow_of(bm + ar, rowmode);
  const float* Arow = A + (size_t)arow*lda;
  int wr = tid >> 2, wkq = (tid & 3) * 4;
  int wrow = bn + wr;
  const float* Wrow = W + (size_t)wrow*K;
  bool wok = wrow < N;

  for (int k0 = 0; k0 < K; k0 += 16) {
    if (k0 + 16 <= K) {       // in-range: vectorized staging
      if constexpr (TM == 64) {
        float4 av = *(const float4*)(Arow + k0 + akq);
        As[akq+0][ar]=av.x; As[akq+1][ar]=av.y; As[akq+2][ar]=av.z; As[akq+3][ar]=av.w;
      } else {
        float2 av = *(const float2*)(Arow + k0 + akq);
        As[akq+0][ar]=av.x; As[akq+1][ar]=av.y;
      }
      float4 wv = make_float4(0.f,0.f,0.f,0.f);
      if (wok) wv = *(const float4*)(Wrow + k0 + wkq);
      Bs[wkq+0][wr]=wv.x; Bs[wkq+1][wr]=wv.y; Bs[wkq+2][wr]=wv.z; Bs[wkq+3][wr]=wv.w;
    } else {                  // ragged tail (K=44->12, K=12): masked scalar, zero-pad
      if constexpr (TM == 64) {
        #pragma unroll
        for (int j = 0; j < 4; ++j) {
          int kg = k0 + akq + j;
          As[akq+j][ar] = (kg < K) ? Arow[kg] : 0.f;
        }
      } else {
        #pragma unroll
        for (int j = 0; j < 2; ++j) {
          int kg = k0 + akq + j;
          As[akq+j][ar] = (kg < K) ? Arow[kg] : 0.f;
        }
      }
      #pragma unroll
      for (int j = 0; j < 4; ++j) {
        int kg = k0 + wkq + j;
        Bs[wkq+j][wr] = (kg < K && wok) ? Wrow[kg] : 0.f;
      }
    }
    __syncthreads();
    #pragma unroll
    for (int kk = 0; kk < 16; ++kk) {
      float a[MR];
      if constexpr (TM == 64) {
        float4 av = *(const float4*)&As[kk][ty*4];
        a[0]=av.x; a[1]=av.y; a[2]=av.z; a[3]=av.w;
      } else {
        float2 av = *(const float2*)&As[kk][ty*2];
        a[0]=av.x; a[1]=av.y;
      }
      float4 bv = *(const float4*)&Bs[kk][tx*4];
      float bb[4] = {bv.x, bv.y, bv.z, bv.w};
      #pragma unroll
      for (int i = 0; i < MR; ++i)
        #pragma unroll
        for (int j = 0; j < 4; ++j) acc[i][j] = fmaf(a[i], bb[j], acc[i][j]);
    }
    __syncthreads();
  }

  #pragma unroll
  for (int i = 0; i < MR; ++i) {
    int m = bm + ty*MR + i;
    float* crow = Cm + (size_t)m*ldc;
    #pragma unroll
    for (int j = 0; j < 4; ++j) {
      int n = bn + tx*4 + j;
      if (n < N) {
        float v = acc[i][j] + (bias ? bias[n] : 0.f);
        crow[n] = apply_act(v, act);
      }
    }
  }
}

// ---------------- depthwise conv, both orientations, BOTH directions per thread + silu ----------------
__global__ void k_conv2(const float* __restrict__ xz2,
                        const float* __restrict__ cw0, const float* __restrict__ cb0,
                        const float* __restrict__ cw1, const float* __restrict__ cb1,
                        float* __restrict__ u4) {
  int i = blockIdx.x*256 + threadIdx.x;
  if (i >= 2*BL*DIN) return;
  int o = i / (BL*DIN);
  int rem = i - o*BL*DIN;
  int d = rem % DIN, t = rem / DIN;
  int l = t % LSEQ;
  const float* cw = o ? cw1 : cw0;
  const float* cb = o ? cb1 : cb0;
  const float* base = xz2 + (size_t)o*BL*768 + (size_t)t*768 + d;
  float x0  = base[0];
  float xm1 = (l>=1)      ? base[-768]   : 0.f;
  float xm2 = (l>=2)      ? base[-2*768] : 0.f;
  float xm3 = (l>=3)      ? base[-3*768] : 0.f;
  float xp1 = (l+1<LSEQ)  ? base[768]    : 0.f;
  float xp2 = (l+2<LSEQ)  ? base[2*768]  : 0.f;
  float xp3 = (l+3<LSEQ)  ? base[3*768]  : 0.f;
  float w0=cw[d*4+0], w1=cw[d*4+1], w2=cw[d*4+2], w3=cw[d*4+3], b=cb[d];
  float sf = b; sf = fmaf(xm3,w0, sf); sf = fmaf(xm2,w1, sf); sf = fmaf(xm1,w2, sf); sf = fmaf(x0,w3, sf);
  float sb = b; sb = fmaf(xp3,w0, sb); sb = fmaf(xp2,w1, sb); sb = fmaf(xp1,w2, sb); sb = fmaf(x0,w3, sb);
  u4[(size_t)(o*2+0)*BL*DIN + rem] = sf*sigf(sf);
  u4[(size_t)(o*2+1)*BL*DIN + rem] = sb*sigf(sb);
}

// ---------------- chunked scan pass A, all 4 (o,dir) pipelines ----------------
__global__ __launch_bounds__(384) void k_scanA(
    const float* __restrict__ u4, const float* __restrict__ delta4,
    const float* __restrict__ xdbl4, const float* __restrict__ Alog0,
    const float* __restrict__ Alog1, float* __restrict__ P, float* __restrict__ Hloc) {
  int bx = blockIdx.x;
  int c = bx & (NC-1);
  int b = (bx >> 6) & (BATCH-1);
  int q = bx >> 7;                  // 0..3 = o*2+dir
  int dir = q & 1, o = q >> 1;
  int d = threadIdx.x;
  const float* Alog  = o ? Alog1 : Alog0;
  const float* u     = u4     + (size_t)q*BL*DIN;
  const float* delta = delta4 + (size_t)q*BL*DIN;
  const float* xdbl  = xdbl4  + (size_t)q*BL*XD;
  float An[DST], h[DST];
  #pragma unroll
  for (int n = 0; n < DST; ++n) { An[n] = -__expf(Alog[d*DST+n]); h[n] = 0.f; }
  float S = 0.f;
  int j0 = c*CSZ;
  for (int j = 0; j < CSZ; ++j) {
    int p = j0 + j;
    int l = dir ? (LSEQ-1-p) : p;
    size_t row = (size_t)b*LSEQ + l;
    float dlt = delta[row*DIN + d];
    float uu  = u[row*DIN + d];
    const float* xr = xdbl + row*XD;
    float du = dlt*uu;
    S += dlt;
    #pragma unroll
    for (int n = 0; n < DST; ++n) {
      float e = __expf(dlt*An[n]);
      h[n] = fmaf(e, h[n], du*xr[DTR+n]);
    }
  }
  size_t base = (((size_t)q*BATCH + b)*DIN + d)*(DST*NC) + c;
  #pragma unroll
  for (int n = 0; n < DST; ++n) {
    P[base + (size_t)n*NC]    = __expf(An[n]*S);   // prod of dA over chunk, closed form
    Hloc[base + (size_t)n*NC] = h[n];
  }
}

// ---------------- pass B: sequential chunk combine ----------------
__global__ void k_scanB(const float* __restrict__ P, const float* __restrict__ Hloc,
                        float* __restrict__ h0) {
  int i = blockIdx.x*256 + threadIdx.x;
  if (i >= 4*BATCH*DIN*DST) return;
  const float* p  = P    + (size_t)i*NC;
  const float* hl = Hloc + (size_t)i*NC;
  float* o        = h0   + (size_t)i*NC;
  float carry = 0.f;
  for (int c = 0; c < NC; ++c) { o[c] = carry; carry = fmaf(p[c], carry, hl[c]); }
}

// ---------------- pass C: seeded scan producing y (+ u*D) ----------------
__global__ __launch_bounds__(384) void k_scanC(
    const float* __restrict__ u4, const float* __restrict__ delta4,
    const float* __restrict__ xdbl4, const float* __restrict__ h0,
    const float* __restrict__ Alog0, const float* __restrict__ Alog1,
    const float* __restrict__ Dp0, const float* __restrict__ Dp1,
    float* __restrict__ y4) {
  int bx = blockIdx.x;
  int c = bx & (NC-1);
  int b = (bx >> 6) & (BATCH-1);
  int q = bx >> 7;
  int dir = q & 1, o = q >> 1;
  int d = threadIdx.x;
  const float* Alog  = o ? Alog1 : Alog0;
  const float* Dp    = o ? Dp1 : Dp0;
  const float* u     = u4     + (size_t)q*BL*DIN;
  const float* delta = delta4 + (size_t)q*BL*DIN;
  const float* xdbl  = xdbl4  + (size_t)q*BL*XD;
  float* y           = y4     + (size_t)q*BL*DIN;
  float An[DST], h[DST];
  size_t hb = (((size_t)q*BATCH + b)*DIN + d)*(DST*NC) + c;
  #pragma unroll
  for (int n = 0; n < DST; ++n) {
    An[n] = -__expf(Alog[d*DST+n]);
    h[n]  = h0[hb + (size_t)n*NC];
  }
  float Dd = Dp[d];
  int j0 = c*CSZ;
  for (int j = 0; j < CSZ; ++j) {
    int p = j0 + j;
    int l = dir ? (LSEQ-1-p) : p;
    size_t row = (size_t)b*LSEQ + l;
    float dlt = delta[row*DIN + d];
    float uu  = u[row*DIN + d];
    const float* xr = xdbl + row*XD;
    float du = dlt*uu;
    float yv = 0.f;
    #pragma unroll
    for (int n = 0; n < DST; ++n) {
      float e = __expf(dlt*An[n]);
      h[n] = fmaf(e, h[n], du*xr[DTR+n]);
      yv = fmaf(h[n], xr[DTR+DST+n], yv);
    }
    yv = fmaf(uu, Dd, yv);
    y[row*DIN + d] = yv;
  }
}

// ---------------- combine dirs + gating: y4[2o] = (y4[2o]+y4[2o+1])*silu(z_o) ----------------
__global__ void k_yfinal(float* __restrict__ y4, const float* __restrict__ xz2) {
  int i = blockIdx.x*256 + threadIdx.x;
  if (i >= 2*BL*DIN) return;
  int o = i / (BL*DIN);
  int rem = i - o*BL*DIN;
  int t = rem / DIN, d = rem - t*DIN;
  float z = xz2[(size_t)o*BL*768 + (size_t)t*768 + DIN + d];
  size_t i0 = (size_t)(o*2)*BL*DIN + rem;
  size_t i1 = (size_t)(o*2+1)*BL*DIN + rem;
  y4[i0] = (y4[i0] + y4[i1]) * siluf(z);
}

// ---------------- ctx partial sums ----------------
__global__ void k_ctxpart(const float* __restrict__ out_h, const float* __restrict__ out_v,
                          float* __restrict__ part) {
  int blk = blockIdx.x;            // BATCH*49
  int b = blk / 49, ch = blk % 49;
  int c = threadIdx.x;             // 192
  int t0 = b*LSEQ + ch*64;
  float s = 0.f;
  for (int k = 0; k < 64; ++k) {
    size_t idx = (size_t)(t0 + k)*CDIM + c;
    s += out_h[idx] + out_v[idx];
  }
  part[(size_t)blk*CDIM + c] = s;
}

// ---------------- gate MLP (single block) ----------------
__global__ void k_gate(const float* __restrict__ part,
                       const float* __restrict__ w1, const float* __restrict__ b1,
                       const float* __restrict__ w2, const float* __restrict__ b2,
                       float* __restrict__ gate) {
  __shared__ float ctxs[BATCH][CDIM];
  __shared__ float hid[BATCH][GH];
  int t = threadIdx.x;             // 256
  for (int idx = t; idx < BATCH*CDIM; idx += 256) {
    int b = idx / CDIM, c = idx % CDIM;
    float s = 0.f;
    for (int k = 0; k < 49; ++k) s += part[(size_t)(b*49+k)*CDIM + c];
    ctxs[b][c] = s * (0.5f/(float)LSEQ);
  }
  __syncthreads();
  if (t < BATCH*GH) {
    int b = t / GH, g = t % GH;
    float s = b1[g];
    for (int c = 0; c < CDIM; ++c) s = fmaf(ctxs[b][c], w1[g*CDIM+c], s);
    hid[b][g] = fmaxf(s, 0.f);
  }
  __syncthreads();
  for (int idx = t; idx < BATCH*CDIM; idx += 256) {
    int b = idx / CDIM, c = idx % CDIM;
    float s = b2[c];
    for (int g = 0; g < GH; ++g) s = fmaf(hid[b][g], w2[c*GH+g], s);
    gate[idx] = sigf(s);
  }
}

// ---------------- fuse ----------------
__global__ void k_fuse(const float* __restrict__ x_tok, const float* __restrict__ out_h,
                       const float* __restrict__ out_v, const float* __restrict__ gate,
                       float* __restrict__ x2) {
  int i = blockIdx.x*256 + threadIdx.x;
  if (i >= BL*CDIM) return;
  int c = i % CDIM;
  int t = i / CDIM;
  int b = t / LSEQ, l = t - b*LSEQ;
  int h = l / WW, w = l - h*WW;
  int lv = w*HH + h;
  float g = gate[b*CDIM + c];
  float ov = out_v[((size_t)(b*LSEQ + lv))*CDIM + c];
  x2[i] = x_tok[i] + g*out_h[i] + (1.f-g)*ov;
}

// ---------------- final ----------------
__global__ void k_final(const float* __restrict__ x2, const float* __restrict__ t2,
                        float* __restrict__ out) {
  int i = blockIdx.x*256 + threadIdx.x;
  if (i >= BL*CDIM) return;
  int l = i % LSEQ;
  int bc = i / LSEQ;
  int c = bc % CDIM, b = bc / CDIM;
  size_t src = ((size_t)(b*LSEQ + l))*CDIM + c;
  out[i] = x2[src] + t2[src];
}

static inline void gemm(hipStream_t s, int TM, const float* A, int lda, int rowmode,
                        const float* W0, const float* W1, const float* b0, const float* b1,
                        int seg, float* C, int ldc, int M, int N, int K, int act) {
  dim3 g(M/TM, (N+63)/64);
  if (TM == 64) k_gemm<64><<<g, 256, 0, s>>>(A, lda, rowmode, W0, W1, b0, b1, seg, C, ldc, N, K, act);
  else          k_gemm<32><<<g, 256, 0, s>>>(A, lda, rowmode, W0, W1, b0, b1, seg, C, ldc, N, K, act);
}

extern "C" void kernel_launch(void* const* d_in, const int* in_sizes, int n_in,
                              void* d_out, int out_size, void* d_ws, size_t ws_size,
                              hipStream_t stream) {
  (void)in_sizes; (void)n_in; (void)out_size; (void)ws_size;
  const float* x   = (const float*)d_in[0];
  const float* n1w = (const float*)d_in[1];
  const float* n2w = (const float*)d_in[2];
  const float* in_w[2]   = {(const float*)d_in[3],  (const float*)d_in[12]};
  const float* conv_w[2] = {(const float*)d_in[4],  (const float*)d_in[13]};
  const float* conv_b[2] = {(const float*)d_in[5],  (const float*)d_in[14]};
  const float* xp_w[2]   = {(const float*)d_in[6],  (const float*)d_in[15]};
  const float* dt_w[2]   = {(const float*)d_in[7],  (const float*)d_in[16]};
  const float* dt_b[2]   = {(const float*)d_in[8],  (const float*)d_in[17]};
  const float* Alog[2]   = {(const float*)d_in[9],  (const float*)d_in[18]};
  const float* Dp[2]     = {(const float*)d_in[10], (const float*)d_in[19]};
  const float* out_w[2]  = {(const float*)d_in[11], (const float*)d_in[20]};
  const float* gw1 = (const float*)d_in[21];
  const float* gb1 = (const float*)d_in[22];
  const float* gw2 = (const float*)d_in[23];
  const float* gb2 = (const float*)d_in[24];
  const float* mw1 = (const float*)d_in[25];
  const float* mb1 = (const float*)d_in[26];
  const float* mw2 = (const float*)d_in[27];
  const float* mb2 = (const float*)d_in[28];

  float* ws = (float*)d_ws;
  float* x_tok  = ws;  ws += 1204224;              // [BL,192]
  float* x_norm = ws;  ws += 1204224;              // later: x2
  float* xz2    = ws;  ws += 9633792;              // [2][BL,768]; later: t1
  float* u4     = ws;  ws += 9633792;              // [4][BL,384]; later: t2
  float* delta4 = ws;  ws += 9633792;              // [4][BL,384]
  float* xdbl4  = ws;  ws += 1103872;              // [4][BL,44]
  float* y4     = ws;  ws += 9633792;              // [4][BL,384]
  float* Pb     = ws;  ws += 3145728;              // [4][B,DIN,DST,NC]
  float* Hl     = ws;  ws += 3145728;
  float* h0b    = ws;  ws += 3145728;
  float* outc   = ws;  ws += 2408448;              // [2][BL,192]: out_h | out_v
  float* part   = ws;  ws += 18816;                // [B,49,192]
  float* gateb  = ws;  ws += 384;
  float* x2  = x_norm;   // aliases (lifetimes disjoint)
  float* xn2 = x_tok;
  float* t1  = xz2;
  float* t2  = u4;
  float* out = (float*)d_out;

  k_rmsnorm1<<<(BL+255)/256, 256, 0, stream>>>(x, n1w, x_tok, x_norm);

  // in_proj, both orientations: M = 2*BL (rowmode 1 gathers v-order rows for o=1)
  gemm(stream, 64, x_norm, CDIM, 1, in_w[0], in_w[1], nullptr, nullptr, BL,
       xz2, 768, 2*BL, 768, CDIM, 0);
  // depthwise conv, both orientations, both directions in one pass
  k_conv2<<<(2*BL*DIN+255)/256, 256, 0, stream>>>(xz2, conv_w[0], conv_b[0],
                                                  conv_w[1], conv_b[1], u4);
  // xproj over all 4 pipelines: M = 4*BL, N=44
  gemm(stream, 32, u4, DIN, 0, xp_w[0], xp_w[1], nullptr, nullptr, 2*BL,
       xdbl4, XD, 4*BL, XD, DIN, 0);
  // dt (softplus) over all 4 pipelines: M = 4*BL, N=384, K=12
  gemm(stream, 64, xdbl4, XD, 0, dt_w[0], dt_w[1], dt_b[0], dt_b[1], 2*BL,
       delta4, DIN, 4*BL, DIN, DTR, 2);
  // scan: all 4 pipelines in each pass
  k_scanA<<<4*BATCH*NC, 384, 0, stream>>>(u4, delta4, xdbl4, Alog[0], Alog[1], Pb, Hl);
  k_scanB<<<(4*BATCH*DIN*DST+255)/256, 256, 0, stream>>>(Pb, Hl, h0b);
  k_scanC<<<4*BATCH*NC, 384, 0, stream>>>(u4, delta4, xdbl4, h0b, Alog[0], Alog[1],
                                          Dp[0], Dp[1], y4);
  k_yfinal<<<(2*BL*DIN+255)/256, 256, 0, stream>>>(y4, xz2);
  // out_proj, both orientations: M = 2*BL (rowmode 2 reads y4[q=0], y4[q=2])
  gemm(stream, 32, y4, DIN, 2, out_w[0], out_w[1], nullptr, nullptr, BL,
       outc, CDIM, 2*BL, CDIM, DIN, 0);

  k_ctxpart<<<BATCH*49, CDIM, 0, stream>>>(outc, outc + (size_t)BL*CDIM, part);
  k_gate<<<1, 256, 0, stream>>>(part, gw1, gb1, gw2, gb2, gateb);
  k_fuse<<<(BL*CDIM+255)/256, 256, 0, stream>>>(x_tok, outc, outc + (size_t)BL*CDIM, gateb, x2);
  k_rmsnorm2<<<(BL+255)/256, 256, 0, stream>>>(x2, n2w, xn2);
  gemm(stream, 64, xn2, CDIM, 0, mw1, nullptr, mb1, nullptr, 1<<30,
       t1, MLPH, BL, MLPH, CDIM, 1);    // gelu
  gemm(stream, 32, t1, MLPH, 0, mw2, nullptr, mb2, nullptr, 1<<30,
       t2, CDIM, BL, CDIM, MLPH, 0);
  k_final<<<(BL*CDIM+255)/256, 256, 0, stream>>>(x2, t2, out);
}

// Round 4
// 520.074 us; speedup vs baseline: 3.1026x; 1.1518x over previous
//
#include <hip/hip_runtime.h>
#include <hip/hip_bf16.h>
#include <math.h>

#define BATCH 2
#define CDIM 192
#define HH 56
#define WW 56
#define LSEQ 3136      // HH*WW
#define BL 6272        // BATCH*LSEQ
#define DIN 384
#define DST 16
#define DTR 12
#define XD 44          // DTR + 2*DST
#define MLPH 768
#define GH 48
#define NC 64          // scan chunks per sequence
#define CSZ 49         // chunk size; NC*CSZ == LSEQ

__device__ __forceinline__ float sigf(float x){ return 1.f/(1.f+__expf(-x)); }
__device__ __forceinline__ float siluf(float x){ return x*sigf(x); }

// ---------------- rmsnorm from NCHW: emits token-major x_tok and normed x_norm ----------------
__global__ void k_rmsnorm1(const float* __restrict__ x, const float* __restrict__ w,
                           float* __restrict__ x_tok, float* __restrict__ x_norm) {
  int t = blockIdx.x*blockDim.x + threadIdx.x;
  if (t >= BL) return;
  int b = t / LSEQ, l = t - b*LSEQ;
  const float* src = x + (size_t)b*CDIM*LSEQ + l;   // x[b][c][l], stride LSEQ over c
  float ss = 0.f;
  for (int c = 0; c < CDIM; ++c) { float v = src[(size_t)c*LSEQ]; ss += v*v; }
  float sc = rsqrtf(ss*(1.f/CDIM) + 1e-6f);
  float* o1 = x_tok  + (size_t)t*CDIM;
  float* o2 = x_norm + (size_t)t*CDIM;
  for (int c = 0; c < CDIM; ++c) { float v = src[(size_t)c*LSEQ]; o1[c] = v; o2[c] = v*sc*w[c]; }
}

// ---------------- rmsnorm on token-major input ----------------
__global__ void k_rmsnorm2(const float* __restrict__ in, const float* __restrict__ w,
                           float* __restrict__ out) {
  int t = blockIdx.x*blockDim.x + threadIdx.x;
  if (t >= BL) return;
  const float* src = in + (size_t)t*CDIM;
  float ss = 0.f;
  for (int c = 0; c < CDIM; ++c) { float v = src[c]; ss += v*v; }
  float sc = rsqrtf(ss*(1.f/CDIM) + 1e-6f);
  float* o = out + (size_t)t*CDIM;
  for (int c = 0; c < CDIM; ++c) o[c] = src[c]*sc*w[c];
}

// ---------------- batched GEMM ----------------
// rowmode 0: arow = m
// rowmode 1: in_proj batched: m in [0,2BL): o=m/BL, t=m%BL; o==0 -> t, o==1 -> v-order gather
// rowmode 2: out_proj batched: m in [0,2BL): arow = (m/BL)*2*BL + (m%BL)  (picks y4[q=0],y4[q=2])
__device__ __forceinline__ int arow_of(int m, int rowmode) {
  if (rowmode == 0) return m;
  int o = m / BL, t = m - o*BL;
  if (rowmode == 2) return o*2*BL + t;
  if (o == 0) return t;
  int b = t / LSEQ, lv = t - b*LSEQ;
  int h = lv % HH, w = lv / HH;     // lv = w*HH + h
  return b*LSEQ + h*WW + w;
}

__device__ __forceinline__ float apply_act(float v, int act) {
  if (act == 1) return 0.5f*v*(1.f+erff(v*0.70710678118654752f));   // exact gelu
  if (act == 2) return (v > 20.f) ? v : log1pf(__expf(v));          // softplus
  return v;
}

// TM x 64 tile, 256 threads, (TM/16)x4 microtile, KT=16.
// Weight/bias segment select: rows >= seg use W1/b1.
template<int TM>
__global__ __launch_bounds__(256) void k_gemm(
    const float* __restrict__ A, int lda, int rowmode,
    const float* __restrict__ W0, const float* __restrict__ W1,
    const float* __restrict__ b0, const float* __restrict__ b1, int seg,
    float* __restrict__ Cm, int ldc, int N, int K, int act) {
  constexpr int MR = TM/16;
  __shared__ __align__(16) float As[16][TM+4];
  __shared__ __align__(16) float Bs[16][68];
  int tid = threadIdx.x;
  int bm = blockIdx.x * TM, bn = blockIdx.y * 64;
  const float* W    = (bm >= seg) ? W1 : W0;
  const float* bias = (bm >= seg) ? b1 : b0;
  int tx = tid & 15, ty = tid >> 4;
  float acc[MR][4];
  #pragma unroll
  for (int i = 0; i < MR; ++i)
    #pragma unroll
    for (int j = 0; j < 4; ++j) acc[i][j] = 0.f;

  int ar, akq;
  if constexpr (TM == 64) { ar = tid >> 2; akq = (tid & 3) * 4; }
  else                    { ar = tid >> 3; akq = (tid & 7) * 2; }
  int arow = arow_of(bm + ar, rowmode);
  const float* Arow = A + (size_t)arow*lda;
  int wr = tid >> 2, wkq = (tid & 3) * 4;
  int wrow = bn + wr;
  const float* Wrow = W + (size_t)wrow*K;
  bool wok = wrow < N;

  for (int k0 = 0; k0 < K; k0 += 16) {
    if (k0 + 16 <= K) {       // in-range: vectorized staging
      if constexpr (TM == 64) {
        float4 av = *(const float4*)(Arow + k0 + akq);
        As[akq+0][ar]=av.x; As[akq+1][ar]=av.y; As[akq+2][ar]=av.z; As[akq+3][ar]=av.w;
      } else {
        float2 av = *(const float2*)(Arow + k0 + akq);
        As[akq+0][ar]=av.x; As[akq+1][ar]=av.y;
      }
      float4 wv = make_float4(0.f,0.f,0.f,0.f);
      if (wok) wv = *(const float4*)(Wrow + k0 + wkq);
      Bs[wkq+0][wr]=wv.x; Bs[wkq+1][wr]=wv.y; Bs[wkq+2][wr]=wv.z; Bs[wkq+3][wr]=wv.w;
    } else {                  // ragged tail (K=44->12, K=12): masked scalar, zero-pad
      if constexpr (TM == 64) {
        #pragma unroll
        for (int j = 0; j < 4; ++j) {
          int kg = k0 + akq + j;
          As[akq+j][ar] = (kg < K) ? Arow[kg] : 0.f;
        }
      } else {
        #pragma unroll
        for (int j = 0; j < 2; ++j) {
          int kg = k0 + akq + j;
          As[akq+j][ar] = (kg < K) ? Arow[kg] : 0.f;
        }
      }
      #pragma unroll
      for (int j = 0; j < 4; ++j) {
        int kg = k0 + wkq + j;
        Bs[wkq+j][wr] = (kg < K && wok) ? Wrow[kg] : 0.f;
      }
    }
    __syncthreads();
    #pragma unroll
    for (int kk = 0; kk < 16; ++kk) {
      float a[MR];
      if constexpr (TM == 64) {
        float4 av = *(const float4*)&As[kk][ty*4];
        a[0]=av.x; a[1]=av.y; a[2]=av.z; a[3]=av.w;
      } else {
        float2 av = *(const float2*)&As[kk][ty*2];
        a[0]=av.x; a[1]=av.y;
      }
      float4 bv = *(const float4*)&Bs[kk][tx*4];
      float bb[4] = {bv.x, bv.y, bv.z, bv.w};
      #pragma unroll
      for (int i = 0; i < MR; ++i)
        #pragma unroll
        for (int j = 0; j < 4; ++j) acc[i][j] = fmaf(a[i], bb[j], acc[i][j]);
    }
    __syncthreads();
  }

  #pragma unroll
  for (int i = 0; i < MR; ++i) {
    int m = bm + ty*MR + i;
    float* crow = Cm + (size_t)m*ldc;
    #pragma unroll
    for (int j = 0; j < 4; ++j) {
      int n = bn + tx*4 + j;
      if (n < N) {
        float v = acc[i][j] + (bias ? bias[n] : 0.f);
        crow[n] = apply_act(v, act);
      }
    }
  }
}

// ---------------- depthwise conv, both orientations, BOTH directions per thread + silu ----------------
__global__ void k_conv2(const float* __restrict__ xz2,
                        const float* __restrict__ cw0, const float* __restrict__ cb0,
                        const float* __restrict__ cw1, const float* __restrict__ cb1,
                        float* __restrict__ u4) {
  int i = blockIdx.x*256 + threadIdx.x;
  if (i >= 2*BL*DIN) return;
  int o = i / (BL*DIN);
  int rem = i - o*BL*DIN;
  int d = rem % DIN, t = rem / DIN;
  int l = t % LSEQ;
  const float* cw = o ? cw1 : cw0;
  const float* cb = o ? cb1 : cb0;
  const float* base = xz2 + (size_t)o*BL*768 + (size_t)t*768 + d;
  float x0  = base[0];
  float xm1 = (l>=1)      ? base[-768]   : 0.f;
  float xm2 = (l>=2)      ? base[-2*768] : 0.f;
  float xm3 = (l>=3)      ? base[-3*768] : 0.f;
  float xp1 = (l+1<LSEQ)  ? base[768]    : 0.f;
  float xp2 = (l+2<LSEQ)  ? base[2*768]  : 0.f;
  float xp3 = (l+3<LSEQ)  ? base[3*768]  : 0.f;
  float w0=cw[d*4+0], w1=cw[d*4+1], w2=cw[d*4+2], w3=cw[d*4+3], b=cb[d];
  float sf = b; sf = fmaf(xm3,w0, sf); sf = fmaf(xm2,w1, sf); sf = fmaf(xm1,w2, sf); sf = fmaf(x0,w3, sf);
  float sb = b; sb = fmaf(xp3,w0, sb); sb = fmaf(xp2,w1, sb); sb = fmaf(xp1,w2, sb); sb = fmaf(x0,w3, sb);
  u4[(size_t)(o*2+0)*BL*DIN + rem] = sf*sigf(sf);
  u4[(size_t)(o*2+1)*BL*DIN + rem] = sb*sigf(sb);
}

// ===== inter-pass buffers P/Hloc/h0 layout: [(q,b)][n][c][d]  (d innermost -> coalesced) =====
// idx(qb,n,c,d) = (((qb*DST + n)*NC + c)*DIN + d

// ---------------- chunked scan pass A, all 4 (o,dir) pipelines ----------------
__global__ __launch_bounds__(384) void k_scanA(
    const float* __restrict__ u4, const float* __restrict__ delta4,
    const float* __restrict__ xdbl4, const float* __restrict__ Alog0,
    const float* __restrict__ Alog1, float* __restrict__ P, float* __restrict__ Hloc) {
  int bx = blockIdx.x;
  int c = bx & (NC-1);
  int b = (bx >> 6) & (BATCH-1);
  int q = bx >> 7;                  // 0..3 = o*2+dir
  int dir = q & 1, o = q >> 1;
  int d = threadIdx.x;
  const float* Alog  = o ? Alog1 : Alog0;
  const float* u     = u4     + (size_t)q*BL*DIN;
  const float* delta = delta4 + (size_t)q*BL*DIN;
  const float* xdbl  = xdbl4  + (size_t)q*BL*XD;
  float An[DST], h[DST];
  #pragma unroll
  for (int n = 0; n < DST; ++n) { An[n] = -__expf(Alog[d*DST+n]); h[n] = 0.f; }
  float S = 0.f;
  int j0 = c*CSZ;
  for (int j = 0; j < CSZ; ++j) {
    int p = j0 + j;
    int l = dir ? (LSEQ-1-p) : p;
    size_t row = (size_t)b*LSEQ + l;
    float dlt = delta[row*DIN + d];
    float uu  = u[row*DIN + d];
    const float* xr = xdbl + row*XD;
    float du = dlt*uu;
    S += dlt;
    #pragma unroll
    for (int n = 0; n < DST; ++n) {
      float e = __expf(dlt*An[n]);
      h[n] = fmaf(e, h[n], du*xr[DTR+n]);
    }
  }
  int qb = q*BATCH + b;
  size_t base = (((size_t)qb*DST)*NC + c)*DIN + d;    // n stride = NC*DIN
  #pragma unroll
  for (int n = 0; n < DST; ++n) {
    P[base + (size_t)n*NC*DIN]    = __expf(An[n]*S);  // prod of dA over chunk, closed form
    Hloc[base + (size_t)n*NC*DIN] = h[n];
  }
}

// ---------------- pass B: chunk combine, one block per (qb,n) chain ----------------
__global__ __launch_bounds__(384) void k_scanB(const float* __restrict__ P,
                                               const float* __restrict__ Hloc,
                                               float* __restrict__ h0) {
  int qb = blockIdx.x >> 4;
  int n  = blockIdx.x & (DST-1);
  int d  = threadIdx.x;
  size_t base = (((size_t)qb*DST + n)*NC)*DIN + d;    // c stride = DIN
  float carry = 0.f;
  for (int c = 0; c < NC; ++c) {
    size_t idx = base + (size_t)c*DIN;
    h0[idx] = carry;
    carry = fmaf(P[idx], carry, Hloc[idx]);
  }
}

// ---------------- pass C: seeded scan producing y (+ u*D) ----------------
__global__ __launch_bounds__(384) void k_scanC(
    const float* __restrict__ u4, const float* __restrict__ delta4,
    const float* __restrict__ xdbl4, const float* __restrict__ h0,
    const float* __restrict__ Alog0, const float* __restrict__ Alog1,
    const float* __restrict__ Dp0, const float* __restrict__ Dp1,
    float* __restrict__ y4) {
  int bx = blockIdx.x;
  int c = bx & (NC-1);
  int b = (bx >> 6) & (BATCH-1);
  int q = bx >> 7;
  int dir = q & 1, o = q >> 1;
  int d = threadIdx.x;
  const float* Alog  = o ? Alog1 : Alog0;
  const float* Dp    = o ? Dp1 : Dp0;
  const float* u     = u4     + (size_t)q*BL*DIN;
  const float* delta = delta4 + (size_t)q*BL*DIN;
  const float* xdbl  = xdbl4  + (size_t)q*BL*XD;
  float* y           = y4     + (size_t)q*BL*DIN;
  int qb = q*BATCH + b;
  size_t hb = (((size_t)qb*DST)*NC + c)*DIN + d;      // n stride = NC*DIN
  float An[DST], h[DST];
  #pragma unroll
  for (int n = 0; n < DST; ++n) {
    An[n] = -__expf(Alog[d*DST+n]);
    h[n]  = h0[hb + (size_t)n*NC*DIN];
  }
  float Dd = Dp[d];
  int j0 = c*CSZ;
  for (int j = 0; j < CSZ; ++j) {
    int p = j0 + j;
    int l = dir ? (LSEQ-1-p) : p;
    size_t row = (size_t)b*LSEQ + l;
    float dlt = delta[row*DIN + d];
    float uu  = u[row*DIN + d];
    const float* xr = xdbl + row*XD;
    float du = dlt*uu;
    float yv = 0.f;
    #pragma unroll
    for (int n = 0; n < DST; ++n) {
      float e = __expf(dlt*An[n]);
      h[n] = fmaf(e, h[n], du*xr[DTR+n]);
      yv = fmaf(h[n], xr[DTR+DST+n], yv);
    }
    yv = fmaf(uu, Dd, yv);
    y[row*DIN + d] = yv;
  }
}

// ---------------- combine dirs + gating: y4[2o] = (y4[2o]+y4[2o+1])*silu(z_o) ----------------
__global__ void k_yfinal(float* __restrict__ y4, const float* __restrict__ xz2) {
  int i = blockIdx.x*256 + threadIdx.x;
  if (i >= 2*BL*DIN) return;
  int o = i / (BL*DIN);
  int rem = i - o*BL*DIN;
  int t = rem / DIN, d = rem - t*DIN;
  float z = xz2[(size_t)o*BL*768 + (size_t)t*768 + DIN + d];
  size_t i0 = (size_t)(o*2)*BL*DIN + rem;
  size_t i1 = (size_t)(o*2+1)*BL*DIN + rem;
  y4[i0] = (y4[i0] + y4[i1]) * siluf(z);
}

// ---------------- ctx partial sums ----------------
__global__ void k_ctxpart(const float* __restrict__ out_h, const float* __restrict__ out_v,
                          float* __restrict__ part) {
  int blk = blockIdx.x;            // BATCH*49
  int b = blk / 49, ch = blk % 49;
  int c = threadIdx.x;             // 192
  int t0 = b*LSEQ + ch*64;
  float s = 0.f;
  for (int k = 0; k < 64; ++k) {
    size_t idx = (size_t)(t0 + k)*CDIM + c;
    s += out_h[idx] + out_v[idx];
  }
  part[(size_t)blk*CDIM + c] = s;
}

// ---------------- gate MLP (single block) ----------------
__global__ void k_gate(const float* __restrict__ part,
                       const float* __restrict__ w1, const float* __restrict__ b1,
                       const float* __restrict__ w2, const float* __restrict__ b2,
                       float* __restrict__ gate) {
  __shared__ float ctxs[BATCH][CDIM];
  __shared__ float hid[BATCH][GH];
  int t = threadIdx.x;             // 256
  for (int idx = t; idx < BATCH*CDIM; idx += 256) {
    int b = idx / CDIM, c = idx % CDIM;
    float s = 0.f;
    for (int k = 0; k < 49; ++k) s += part[(size_t)(b*49+k)*CDIM + c];
    ctxs[b][c] = s * (0.5f/(float)LSEQ);
  }
  __syncthreads();
  if (t < BATCH*GH) {
    int b = t / GH, g = t % GH;
    float s = b1[g];
    for (int c = 0; c < CDIM; ++c) s = fmaf(ctxs[b][c], w1[g*CDIM+c], s);
    hid[b][g] = fmaxf(s, 0.f);
  }
  __syncthreads();
  for (int idx = t; idx < BATCH*CDIM; idx += 256) {
    int b = idx / CDIM, c = idx % CDIM;
    float s = b2[c];
    for (int g = 0; g < GH; ++g) s = fmaf(hid[b][g], w2[c*GH+g], s);
    gate[idx] = sigf(s);
  }
}

// ---------------- fuse ----------------
__global__ void k_fuse(const float* __restrict__ x_tok, const float* __restrict__ out_h,
                       const float* __restrict__ out_v, const float* __restrict__ gate,
                       float* __restrict__ x2) {
  int i = blockIdx.x*256 + threadIdx.x;
  if (i >= BL*CDIM) return;
  int c = i % CDIM;
  int t = i / CDIM;
  int b = t / LSEQ, l = t - b*LSEQ;
  int h = l / WW, w = l - h*WW;
  int lv = w*HH + h;
  float g = gate[b*CDIM + c];
  float ov = out_v[((size_t)(b*LSEQ + lv))*CDIM + c];
  x2[i] = x_tok[i] + g*out_h[i] + (1.f-g)*ov;
}

// ---------------- final ----------------
__global__ void k_final(const float* __restrict__ x2, const float* __restrict__ t2,
                        float* __restrict__ out) {
  int i = blockIdx.x*256 + threadIdx.x;
  if (i >= BL*CDIM) return;
  int l = i % LSEQ;
  int bc = i / LSEQ;
  int c = bc % CDIM, b = bc / CDIM;
  size_t src = ((size_t)(b*LSEQ + l))*CDIM + c;
  out[i] = x2[src] + t2[src];
}

static inline void gemm(hipStream_t s, int TM, const float* A, int lda, int rowmode,
                        const float* W0, const float* W1, const float* b0, const float* b1,
                        int seg, float* C, int ldc, int M, int N, int K, int act) {
  dim3 g(M/TM, (N+63)/64);
  if (TM == 64) k_gemm<64><<<g, 256, 0, s>>>(A, lda, rowmode, W0, W1, b0, b1, seg, C, ldc, N, K, act);
  else          k_gemm<32><<<g, 256, 0, s>>>(A, lda, rowmode, W0, W1, b0, b1, seg, C, ldc, N, K, act);
}

extern "C" void kernel_launch(void* const* d_in, const int* in_sizes, int n_in,
                              void* d_out, int out_size, void* d_ws, size_t ws_size,
                              hipStream_t stream) {
  (void)in_sizes; (void)n_in; (void)out_size; (void)ws_size;
  const float* x   = (const float*)d_in[0];
  const float* n1w = (const float*)d_in[1];
  const float* n2w = (const float*)d_in[2];
  const float* in_w[2]   = {(const float*)d_in[3],  (const float*)d_in[12]};
  const float* conv_w[2] = {(const float*)d_in[4],  (const float*)d_in[13]};
  const float* conv_b[2] = {(const float*)d_in[5],  (const float*)d_in[14]};
  const float* xp_w[2]   = {(const float*)d_in[6],  (const float*)d_in[15]};
  const float* dt_w[2]   = {(const float*)d_in[7],  (const float*)d_in[16]};
  const float* dt_b[2]   = {(const float*)d_in[8],  (const float*)d_in[17]};
  const float* Alog[2]   = {(const float*)d_in[9],  (const float*)d_in[18]};
  const float* Dp[2]     = {(const float*)d_in[10], (const float*)d_in[19]};
  const float* out_w[2]  = {(const float*)d_in[11], (const float*)d_in[20]};
  const float* gw1 = (const float*)d_in[21];
  const float* gb1 = (const float*)d_in[22];
  const float* gw2 = (const float*)d_in[23];
  const float* gb2 = (const float*)d_in[24];
  const float* mw1 = (const float*)d_in[25];
  const float* mb1 = (const float*)d_in[26];
  const float* mw2 = (const float*)d_in[27];
  const float* mb2 = (const float*)d_in[28];

  float* ws = (float*)d_ws;
  float* x_tok  = ws;  ws += 1204224;              // [BL,192]
  float* x_norm = ws;  ws += 1204224;              // later: x2
  float* xz2    = ws;  ws += 9633792;              // [2][BL,768]; later: t1
  float* u4     = ws;  ws += 9633792;              // [4][BL,384]; later: t2
  float* delta4 = ws;  ws += 9633792;              // [4][BL,384]
  float* xdbl4  = ws;  ws += 1103872;              // [4][BL,44]
  float* y4     = ws;  ws += 9633792;              // [4][BL,384]
  float* Pb     = ws;  ws += 3145728;              // [(q,b)][n][c][d]
  float* Hl     = ws;  ws += 3145728;
  float* h0b    = ws;  ws += 3145728;
  float* outc   = ws;  ws += 2408448;              // [2][BL,192]: out_h | out_v
  float* part   = ws;  ws += 18816;                // [B,49,192]
  float* gateb  = ws;  ws += 384;
  float* x2  = x_norm;   // aliases (lifetimes disjoint)
  float* xn2 = x_tok;
  float* t1  = xz2;
  float* t2  = u4;
  float* out = (float*)d_out;

  k_rmsnorm1<<<(BL+255)/256, 256, 0, stream>>>(x, n1w, x_tok, x_norm);

  // in_proj, both orientations: M = 2*BL (rowmode 1 gathers v-order rows for o=1)
  gemm(stream, 64, x_norm, CDIM, 1, in_w[0], in_w[1], nullptr, nullptr, BL,
       xz2, 768, 2*BL, 768, CDIM, 0);
  // depthwise conv, both orientations, both directions in one pass
  k_conv2<<<(2*BL*DIN+255)/256, 256, 0, stream>>>(xz2, conv_w[0], conv_b[0],
                                                  conv_w[1], conv_b[1], u4);
  // xproj over all 4 pipelines: M = 4*BL, N=44
  gemm(stream, 32, u4, DIN, 0, xp_w[0], xp_w[1], nullptr, nullptr, 2*BL,
       xdbl4, XD, 4*BL, XD, DIN, 0);
  // dt (softplus) over all 4 pipelines: M = 4*BL, N=384, K=12
  gemm(stream, 64, xdbl4, XD, 0, dt_w[0], dt_w[1], dt_b[0], dt_b[1], 2*BL,
       delta4, DIN, 4*BL, DIN, DTR, 2);
  // scan: all 4 pipelines in each pass
  k_scanA<<<4*BATCH*NC, 384, 0, stream>>>(u4, delta4, xdbl4, Alog[0], Alog[1], Pb, Hl);
  k_scanB<<<4*BATCH*DST, 384, 0, stream>>>(Pb, Hl, h0b);
  k_scanC<<<4*BATCH*NC, 384, 0, stream>>>(u4, delta4, xdbl4, h0b, Alog[0], Alog[1],
                                          Dp[0], Dp[1], y4);
  k_yfinal<<<(2*BL*DIN+255)/256, 256, 0, stream>>>(y4, xz2);
  // out_proj, both orientations: M = 2*BL (rowmode 2 reads y4[q=0], y4[q=2])
  gemm(stream, 32, y4, DIN, 2, out_w[0], out_w[1], nullptr, nullptr, BL,
       outc, CDIM, 2*BL, CDIM, DIN, 0);

  k_ctxpart<<<BATCH*49, CDIM, 0, stream>>>(outc, outc + (size_t)BL*CDIM, part);
  k_gate<<<1, 256, 0, stream>>>(part, gw1, gb1, gw2, gb2, gateb);
  k_fuse<<<(BL*CDIM+255)/256, 256, 0, stream>>>(x_tok, outc, outc + (size_t)BL*CDIM, gateb, x2);
  k_rmsnorm2<<<(BL+255)/256, 256, 0, stream>>>(x2, n2w, xn2);
  gemm(stream, 64, xn2, CDIM, 0, mw1, nullptr, mb1, nullptr, 1<<30,
       t1, MLPH, BL, MLPH, CDIM, 1);    // gelu
  gemm(stream, 32, t1, MLPH, 0, mw2, nullptr, mb2, nullptr, 1<<30,
       t2, CDIM, BL, CDIM, MLPH, 0);
  k_final<<<(BL*CDIM+255)/256, 256, 0, stream>>>(x2, t2, out);
}

// Round 5
// 368.391 us; speedup vs baseline: 4.3800x; 1.4117x over previous
//
#include <hip/hip_runtime.h>
#include <hip/hip_bf16.h>
#include <math.h>

#define BATCH 2
#define CDIM 192
#define HH 56
#define WW 56
#define LSEQ 3136      // HH*WW
#define BL 6272        // BATCH*LSEQ
#define DIN 384
#define DST 16
#define DTR 12
#define XD 44          // DTR + 2*DST
#define MLPH 768
#define GH 48
#define NC 64          // scan chunks per sequence
#define CSZ 49         // chunk size; NC*CSZ == LSEQ

typedef __attribute__((ext_vector_type(8))) short short8;
typedef __attribute__((ext_vector_type(4))) float f32x4;

__device__ __forceinline__ float sigf(float x){ return 1.f/(1.f+__expf(-x)); }
__device__ __forceinline__ float siluf(float x){ return x*sigf(x); }

__device__ __forceinline__ unsigned short f2bf(float f) {
  __hip_bfloat16 h = __float2bfloat16(f);   // RNE; compiler emits v_cvt_pk_bf16_f32 for pairs
  return *reinterpret_cast<unsigned short*>(&h);
}

// ---------------- rmsnorm from NCHW: emits token-major x_tok and normed x_norm ----------------
__global__ void k_rmsnorm1(const float* __restrict__ x, const float* __restrict__ w,
                           float* __restrict__ x_tok, float* __restrict__ x_norm) {
  int t = blockIdx.x*blockDim.x + threadIdx.x;
  if (t >= BL) return;
  int b = t / LSEQ, l = t - b*LSEQ;
  const float* src = x + (size_t)b*CDIM*LSEQ + l;   // x[b][c][l], stride LSEQ over c
  float ss = 0.f;
  for (int c = 0; c < CDIM; ++c) { float v = src[(size_t)c*LSEQ]; ss += v*v; }
  float sc = rsqrtf(ss*(1.f/CDIM) + 1e-6f);
  float* o1 = x_tok  + (size_t)t*CDIM;
  float* o2 = x_norm + (size_t)t*CDIM;
  for (int c = 0; c < CDIM; ++c) { float v = src[(size_t)c*LSEQ]; o1[c] = v; o2[c] = v*sc*w[c]; }
}

// ---------------- rmsnorm on token-major input ----------------
__global__ void k_rmsnorm2(const float* __restrict__ in, const float* __restrict__ w,
                           float* __restrict__ out) {
  int t = blockIdx.x*blockDim.x + threadIdx.x;
  if (t >= BL) return;
  const float* src = in + (size_t)t*CDIM;
  float ss = 0.f;
  for (int c = 0; c < CDIM; ++c) { float v = src[c]; ss += v*v; }
  float sc = rsqrtf(ss*(1.f/CDIM) + 1e-6f);
  float* o = out + (size_t)t*CDIM;
  for (int c = 0; c < CDIM; ++c) o[c] = src[c]*sc*w[c];
}

// ---------------- row mapping for batched GEMMs ----------------
// rowmode 0: arow = m
// rowmode 1: in_proj batched: m in [0,2BL): o=m/BL, t=m%BL; o==0 -> t, o==1 -> v-order gather
// rowmode 2: out_proj batched: m in [0,2BL): arow = (m/BL)*2*BL + (m%BL)  (picks y4[q=0],y4[q=2])
__device__ __forceinline__ int arow_of(int m, int rowmode) {
  if (rowmode == 0) return m;
  int o = m / BL, t = m - o*BL;
  if (rowmode == 2) return o*2*BL + t;
  if (o == 0) return t;
  int b = t / LSEQ, lv = t - b*LSEQ;
  int h = lv % HH, w = lv / HH;     // lv = w*HH + h
  return b*LSEQ + h*WW + w;
}

__device__ __forceinline__ float apply_act(float v, int act) {
  if (act == 1) return 0.5f*v*(1.f+erff(v*0.70710678118654752f));   // exact gelu
  return v;
}

// ---------------- bf16 MFMA GEMM: C[m][n] = act( A[maprow(m)][:K] . W[n][:K] + bias[n] ) ----------------
// BM x 64 tile, BK=32, 256 threads = 4 waves as 2x2.
// LDS: row-major [rows][BK+8] bf16 (padded; fragment reads <=2-way bank alias).
// Fragment mapping (verified m89/m92): A/B lane reads 8 consecutive k at row (lane&15),
// k-offset (lane>>4)*8; D: col = lane&15, row = (lane>>4)*4 + reg.
template<int BM>
__global__ __launch_bounds__(256) void k_gemm_mfma(
    const float* __restrict__ A, int lda, int rowmode,
    const float* __restrict__ W0, const float* __restrict__ W1,
    const float* __restrict__ b0, const float* __restrict__ b1, int seg,
    float* __restrict__ Cm, int ldc, int N, int K, int act) {
  constexpr int BN = 64, BK = 32;
  constexpr int LDT = BK + 8;            // shorts per LDS row (80 B)
  constexpr int FM = BM/32;              // frags per wave in m (128->4, 64->2)
  constexpr int FN = 2;                  // frags per wave in n (32 cols)
  __shared__ __align__(16) unsigned short As[BM*LDT];
  __shared__ __align__(16) unsigned short Bs[BN*LDT];
  int tid = threadIdx.x;
  int bm = blockIdx.x*BM, bn = blockIdx.y*BN;
  const float* W    = (bm >= seg) ? W1 : W0;
  const float* bias = (bm >= seg) ? b1 : b0;
  int lane = tid & 63, wave = tid >> 6;
  int wm = wave >> 1, wn = wave & 1;

  f32x4 acc[FM][FN];
  #pragma unroll
  for (int i = 0; i < FM; ++i)
    #pragma unroll
    for (int j = 0; j < FN; ++j) acc[i][j] = (f32x4){0.f,0.f,0.f,0.f};

  // staging assignment: thread covers row sr (+64 for BM=128), 8 k-values at skq
  int sr = tid >> 2;
  int skq = (tid & 3) * 8;
  int arowidx[BM/64];
  #pragma unroll
  for (int i = 0; i < BM/64; ++i) arowidx[i] = arow_of(bm + sr + i*64, rowmode);
  const float* Wrow = W + (size_t)(bn + sr)*K;
  bool wok = (bn + sr) < N;

  for (int k0 = 0; k0 < K; k0 += BK) {
    #pragma unroll
    for (int i = 0; i < BM/64; ++i) {
      const float* src = A + (size_t)arowidx[i]*lda + k0 + skq;
      short8 t;
      if (k0 + skq + 8 <= K) {
        float4 v0 = *(const float4*)src;
        float4 v1 = *(const float4*)(src+4);
        t[0]=f2bf(v0.x); t[1]=f2bf(v0.y); t[2]=f2bf(v0.z); t[3]=f2bf(v0.w);
        t[4]=f2bf(v1.x); t[5]=f2bf(v1.y); t[6]=f2bf(v1.z); t[7]=f2bf(v1.w);
      } else {
        #pragma unroll
        for (int j = 0; j < 8; ++j) {
          int kg = k0 + skq + j;
          t[j] = (kg < K) ? (short)f2bf(src[j]) : (short)0;
        }
      }
      *(short8*)&As[(sr + i*64)*LDT + skq] = t;
    }
    {
      short8 t;
      if (wok && k0 + skq + 8 <= K) {
        float4 v0 = *(const float4*)(Wrow + k0 + skq);
        float4 v1 = *(const float4*)(Wrow + k0 + skq + 4);
        t[0]=f2bf(v0.x); t[1]=f2bf(v0.y); t[2]=f2bf(v0.z); t[3]=f2bf(v0.w);
        t[4]=f2bf(v1.x); t[5]=f2bf(v1.y); t[6]=f2bf(v1.z); t[7]=f2bf(v1.w);
      } else {
        #pragma unroll
        for (int j = 0; j < 8; ++j) {
          int kg = k0 + skq + j;
          t[j] = (wok && kg < K) ? (short)f2bf(Wrow[kg]) : (short)0;
        }
      }
      *(short8*)&Bs[sr*LDT + skq] = t;
    }
    __syncthreads();

    int fr = lane & 15;
    int kq = (lane >> 4) * 8;
    short8 af[FM], bfr[FN];
    #pragma unroll
    for (int i = 0; i < FM; ++i)
      af[i] = *(const short8*)&As[(wm*(BM/2) + i*16 + fr)*LDT + kq];
    #pragma unroll
    for (int j = 0; j < FN; ++j)
      bfr[j] = *(const short8*)&Bs[(wn*32 + j*16 + fr)*LDT + kq];
    #pragma unroll
    for (int i = 0; i < FM; ++i)
      #pragma unroll
      for (int j = 0; j < FN; ++j)
        acc[i][j] = __builtin_amdgcn_mfma_f32_16x16x32_bf16(af[i], bfr[j], acc[i][j], 0, 0, 0);
    __syncthreads();
  }

  int nl = lane & 15, m4 = (lane >> 4) * 4;
  #pragma unroll
  for (int i = 0; i < FM; ++i) {
    #pragma unroll
    for (int j = 0; j < FN; ++j) {
      #pragma unroll
      for (int r = 0; r < 4; ++r) {
        int m = bm + wm*(BM/2) + i*16 + m4 + r;
        int n = bn + wn*32 + j*16 + nl;
        if (n < N) {
          float v = acc[i][j][r] + (bias ? bias[n] : 0.f);
          Cm[(size_t)m*ldc + n] = apply_act(v, act);
        }
      }
    }
  }
}

// ---------------- dt projection + softplus: delta[row][d] = sp(xdbl[row][:12].dtw[d] + dtb[d]) ----------------
__global__ __launch_bounds__(384) void k_dt(const float* __restrict__ xdbl4,
    const float* __restrict__ w0, const float* __restrict__ w1,
    const float* __restrict__ bb0, const float* __restrict__ bb1,
    float* __restrict__ delta4) {
  int row = blockIdx.x;               // 0..4BL-1
  int d = threadIdx.x;
  int o = row / (2*BL);
  const float* wR = o ? w1 : w0;
  const float* bR = o ? bb1 : bb0;
  __shared__ float xr[DTR];
  if (d < DTR) xr[d] = xdbl4[(size_t)row*XD + d];
  __syncthreads();
  float s = bR[d];
  #pragma unroll
  for (int k = 0; k < DTR; ++k) s = fmaf(xr[k], wR[d*DTR + k], s);
  delta4[(size_t)row*DIN + d] = (s > 20.f) ? s : log1pf(__expf(s));
}

// ---------------- depthwise conv, both orientations, BOTH directions per thread + silu ----------------
__global__ void k_conv2(const float* __restrict__ xz2,
                        const float* __restrict__ cw0, const float* __restrict__ cb0,
                        const float* __restrict__ cw1, const float* __restrict__ cb1,
                        float* __restrict__ u4) {
  int i = blockIdx.x*256 + threadIdx.x;
  if (i >= 2*BL*DIN) return;
  int o = i / (BL*DIN);
  int rem = i - o*BL*DIN;
  int d = rem % DIN, t = rem / DIN;
  int l = t % LSEQ;
  const float* cw = o ? cw1 : cw0;
  const float* cb = o ? cb1 : cb0;
  const float* base = xz2 + (size_t)o*BL*768 + (size_t)t*768 + d;
  float x0  = base[0];
  float xm1 = (l>=1)      ? base[-768]   : 0.f;
  float xm2 = (l>=2)      ? base[-2*768] : 0.f;
  float xm3 = (l>=3)      ? base[-3*768] : 0.f;
  float xp1 = (l+1<LSEQ)  ? base[768]    : 0.f;
  float xp2 = (l+2<LSEQ)  ? base[2*768]  : 0.f;
  float xp3 = (l+3<LSEQ)  ? base[3*768]  : 0.f;
  float w0=cw[d*4+0], w1=cw[d*4+1], w2=cw[d*4+2], w3=cw[d*4+3], b=cb[d];
  float sf = b; sf = fmaf(xm3,w0, sf); sf = fmaf(xm2,w1, sf); sf = fmaf(xm1,w2, sf); sf = fmaf(x0,w3, sf);
  float sb = b; sb = fmaf(xp3,w0, sb); sb = fmaf(xp2,w1, sb); sb = fmaf(xp1,w2, sb); sb = fmaf(x0,w3, sb);
  u4[(size_t)(o*2+0)*BL*DIN + rem] = sf*sigf(sf);
  u4[(size_t)(o*2+1)*BL*DIN + rem] = sb*sigf(sb);
}

// ===== inter-pass buffers P/Hloc/h0 layout: [(q,b)][n][c][d]  (d innermost -> coalesced) =====

// ---------------- chunked scan pass A, all 4 (o,dir) pipelines ----------------
__global__ __launch_bounds__(384) void k_scanA(
    const float* __restrict__ u4, const float* __restrict__ delta4,
    const float* __restrict__ xdbl4, const float* __restrict__ Alog0,
    const float* __restrict__ Alog1, float* __restrict__ P, float* __restrict__ Hloc) {
  int bx = blockIdx.x;
  int c = bx & (NC-1);
  int b = (bx >> 6) & (BATCH-1);
  int q = bx >> 7;                  // 0..3 = o*2+dir
  int dir = q & 1, o = q >> 1;
  int d = threadIdx.x;
  const float* Alog  = o ? Alog1 : Alog0;
  const float* u     = u4     + (size_t)q*BL*DIN;
  const float* delta = delta4 + (size_t)q*BL*DIN;
  const float* xdbl  = xdbl4  + (size_t)q*BL*XD;
  float An[DST], h[DST];
  #pragma unroll
  for (int n = 0; n < DST; ++n) { An[n] = -__expf(Alog[d*DST+n]); h[n] = 0.f; }
  float S = 0.f;
  int j0 = c*CSZ;
  for (int j = 0; j < CSZ; ++j) {
    int p = j0 + j;
    int l = dir ? (LSEQ-1-p) : p;
    size_t row = (size_t)b*LSEQ + l;
    float dlt = delta[row*DIN + d];
    float uu  = u[row*DIN + d];
    const float* xr = xdbl + row*XD;
    float du = dlt*uu;
    S += dlt;
    #pragma unroll
    for (int n = 0; n < DST; ++n) {
      float e = __expf(dlt*An[n]);
      h[n] = fmaf(e, h[n], du*xr[DTR+n]);
    }
  }
  int qb = q*BATCH + b;
  size_t base = (((size_t)qb*DST)*NC + c)*DIN + d;    // n stride = NC*DIN
  #pragma unroll
  for (int n = 0; n < DST; ++n) {
    P[base + (size_t)n*NC*DIN]    = __expf(An[n]*S);  // prod of dA over chunk, closed form
    Hloc[base + (size_t)n*NC*DIN] = h[n];
  }
}

// ---------------- pass B: chunk combine, one block per (qb,n) chain ----------------
__global__ __launch_bounds__(384) void k_scanB(const float* __restrict__ P,
                                               const float* __restrict__ Hloc,
                                               float* __restrict__ h0) {
  int qb = blockIdx.x >> 4;
  int n  = blockIdx.x & (DST-1);
  int d  = threadIdx.x;
  size_t base = (((size_t)qb*DST + n)*NC)*DIN + d;    // c stride = DIN
  float carry = 0.f;
  for (int c = 0; c < NC; ++c) {
    size_t idx = base + (size_t)c*DIN;
    h0[idx] = carry;
    carry = fmaf(P[idx], carry, Hloc[idx]);
  }
}

// ---------------- pass C: seeded scan producing y (+ u*D) ----------------
__global__ __launch_bounds__(384) void k_scanC(
    const float* __restrict__ u4, const float* __restrict__ delta4,
    const float* __restrict__ xdbl4, const float* __restrict__ h0,
    const float* __restrict__ Alog0, const float* __restrict__ Alog1,
    const float* __restrict__ Dp0, const float* __restrict__ Dp1,
    float* __restrict__ y4) {
  int bx = blockIdx.x;
  int c = bx & (NC-1);
  int b = (bx >> 6) & (BATCH-1);
  int q = bx >> 7;
  int dir = q & 1, o = q >> 1;
  int d = threadIdx.x;
  const float* Alog  = o ? Alog1 : Alog0;
  const float* Dp    = o ? Dp1 : Dp0;
  const float* u     = u4     + (size_t)q*BL*DIN;
  const float* delta = delta4 + (size_t)q*BL*DIN;
  const float* xdbl  = xdbl4  + (size_t)q*BL*XD;
  float* y           = y4     + (size_t)q*BL*DIN;
  int qb = q*BATCH + b;
  size_t hb = (((size_t)qb*DST)*NC + c)*DIN + d;      // n stride = NC*DIN
  float An[DST], h[DST];
  #pragma unroll
  for (int n = 0; n < DST; ++n) {
    An[n] = -__expf(Alog[d*DST+n]);
    h[n]  = h0[hb + (size_t)n*NC*DIN];
  }
  float Dd = Dp[d];
  int j0 = c*CSZ;
  for (int j = 0; j < CSZ; ++j) {
    int p = j0 + j;
    int l = dir ? (LSEQ-1-p) : p;
    size_t row = (size_t)b*LSEQ + l;
    float dlt = delta[row*DIN + d];
    float uu  = u[row*DIN + d];
    const float* xr = xdbl + row*XD;
    float du = dlt*uu;
    float yv = 0.f;
    #pragma unroll
    for (int n = 0; n < DST; ++n) {
      float e = __expf(dlt*An[n]);
      h[n] = fmaf(e, h[n], du*xr[DTR+n]);
      yv = fmaf(h[n], xr[DTR+DST+n], yv);
    }
    yv = fmaf(uu, Dd, yv);
    y[row*DIN + d] = yv;
  }
}

// ---------------- combine dirs + gating: y4[2o] = (y4[2o]+y4[2o+1])*silu(z_o) ----------------
__global__ void k_yfinal(float* __restrict__ y4, const float* __restrict__ xz2) {
  int i = blockIdx.x*256 + threadIdx.x;
  if (i >= 2*BL*DIN) return;
  int o = i / (BL*DIN);
  int rem = i - o*BL*DIN;
  int t = rem / DIN, d = rem - t*DIN;
  float z = xz2[(size_t)o*BL*768 + (size_t)t*768 + DIN + d];
  size_t i0 = (size_t)(o*2)*BL*DIN + rem;
  size_t i1 = (size_t)(o*2+1)*BL*DIN + rem;
  y4[i0] = (y4[i0] + y4[i1]) * siluf(z);
}

// ---------------- ctx partial sums ----------------
__global__ void k_ctxpart(const float* __restrict__ out_h, const float* __restrict__ out_v,
                          float* __restrict__ part) {
  int blk = blockIdx.x;            // BATCH*49
  int b = blk / 49, ch = blk % 49;
  int c = threadIdx.x;             // 192
  int t0 = b*LSEQ + ch*64;
  float s = 0.f;
  for (int k = 0; k < 64; ++k) {
    size_t idx = (size_t)(t0 + k)*CDIM + c;
    s += out_h[idx] + out_v[idx];
  }
  part[(size_t)blk*CDIM + c] = s;
}

// ---------------- gate MLP (single block) ----------------
__global__ void k_gate(const float* __restrict__ part,
                       const float* __restrict__ w1, const float* __restrict__ b1,
                       const float* __restrict__ w2, const float* __restrict__ b2,
                       float* __restrict__ gate) {
  __shared__ float ctxs[BATCH][CDIM];
  __shared__ float hid[BATCH][GH];
  int t = threadIdx.x;             // 256
  for (int idx = t; idx < BATCH*CDIM; idx += 256) {
    int b = idx / CDIM, c = idx % CDIM;
    float s = 0.f;
    for (int k = 0; k < 49; ++k) s += part[(size_t)(b*49+k)*CDIM + c];
    ctxs[b][c] = s * (0.5f/(float)LSEQ);
  }
  __syncthreads();
  if (t < BATCH*GH) {
    int b = t / GH, g = t % GH;
    float s = b1[g];
    for (int c = 0; c < CDIM; ++c) s = fmaf(ctxs[b][c], w1[g*CDIM+c], s);
    hid[b][g] = fmaxf(s, 0.f);
  }
  __syncthreads();
  for (int idx = t; idx < BATCH*CDIM; idx += 256) {
    int b = idx / CDIM, c = idx % CDIM;
    float s = b2[c];
    for (int g = 0; g < GH; ++g) s = fmaf(hid[b][g], w2[c*GH+g], s);
    gate[idx] = sigf(s);
  }
}

// ---------------- fuse ----------------
__global__ void k_fuse(const float* __restrict__ x_tok, const float* __restrict__ out_h,
                       const float* __restrict__ out_v, const float* __restrict__ gate,
                       float* __restrict__ x2) {
  int i = blockIdx.x*256 + threadIdx.x;
  if (i >= BL*CDIM) return;
  int c = i % CDIM;
  int t = i / CDIM;
  int b = t / LSEQ, l = t - b*LSEQ;
  int h = l / WW, w = l - h*WW;
  int lv = w*HH + h;
  float g = gate[b*CDIM + c];
  float ov = out_v[((size_t)(b*LSEQ + lv))*CDIM + c];
  x2[i] = x_tok[i] + g*out_h[i] + (1.f-g)*ov;
}

// ---------------- final ----------------
__global__ void k_final(const float* __restrict__ x2, const float* __restrict__ t2,
                        float* __restrict__ out) {
  int i = blockIdx.x*256 + threadIdx.x;
  if (i >= BL*CDIM) return;
  int l = i % LSEQ;
  int bc = i / LSEQ;
  int c = bc % CDIM, b = bc / CDIM;
  size_t src = ((size_t)(b*LSEQ + l))*CDIM + c;
  out[i] = x2[src] + t2[src];
}

static inline void gemm(hipStream_t s, int BM_, const float* A, int lda, int rowmode,
                        const float* W0, const float* W1, const float* b0, const float* b1,
                        int seg, float* C, int ldc, int M, int N, int K, int act) {
  dim3 g(M/BM_, (N+63)/64);
  if (BM_ == 128) k_gemm_mfma<128><<<g, 256, 0, s>>>(A, lda, rowmode, W0, W1, b0, b1, seg, C, ldc, N, K, act);
  else            k_gemm_mfma<64><<<g, 256, 0, s>>>(A, lda, rowmode, W0, W1, b0, b1, seg, C, ldc, N, K, act);
}

extern "C" void kernel_launch(void* const* d_in, const int* in_sizes, int n_in,
                              void* d_out, int out_size, void* d_ws, size_t ws_size,
                              hipStream_t stream) {
  (void)in_sizes; (void)n_in; (void)out_size; (void)ws_size;
  const float* x   = (const float*)d_in[0];
  const float* n1w = (const float*)d_in[1];
  const float* n2w = (const float*)d_in[2];
  const float* in_w[2]   = {(const float*)d_in[3],  (const float*)d_in[12]};
  const float* conv_w[2] = {(const float*)d_in[4],  (const float*)d_in[13]};
  const float* conv_b[2] = {(const float*)d_in[5],  (const float*)d_in[14]};
  const float* xp_w[2]   = {(const float*)d_in[6],  (const float*)d_in[15]};
  const float* dt_w[2]   = {(const float*)d_in[7],  (const float*)d_in[16]};
  const float* dt_b[2]   = {(const float*)d_in[8],  (const float*)d_in[17]};
  const float* Alog[2]   = {(const float*)d_in[9],  (const float*)d_in[18]};
  const float* Dp[2]     = {(const float*)d_in[10], (const float*)d_in[19]};
  const float* out_w[2]  = {(const float*)d_in[11], (const float*)d_in[20]};
  const float* gw1 = (const float*)d_in[21];
  const float* gb1 = (const float*)d_in[22];
  const float* gw2 = (const float*)d_in[23];
  const float* gb2 = (const float*)d_in[24];
  const float* mw1 = (const float*)d_in[25];
  const float* mb1 = (const float*)d_in[26];
  const float* mw2 = (const float*)d_in[27];
  const float* mb2 = (const float*)d_in[28];

  float* ws = (float*)d_ws;
  float* x_tok  = ws;  ws += 1204224;              // [BL,192]
  float* x_norm = ws;  ws += 1204224;              // later: x2
  float* xz2    = ws;  ws += 9633792;              // [2][BL,768]; later: t1
  float* u4     = ws;  ws += 9633792;              // [4][BL,384]; later: t2
  float* delta4 = ws;  ws += 9633792;              // [4][BL,384]
  float* xdbl4  = ws;  ws += 1103872;              // [4][BL,44]
  float* y4     = ws;  ws += 9633792;              // [4][BL,384]
  float* Pb     = ws;  ws += 3145728;              // [(q,b)][n][c][d]
  float* Hl     = ws;  ws += 3145728;
  float* h0b    = ws;  ws += 3145728;
  float* outc   = ws;  ws += 2408448;              // [2][BL,192]: out_h | out_v
  float* part   = ws;  ws += 18816;                // [B,49,192]
  float* gateb  = ws;  ws += 384;
  float* x2  = x_norm;   // aliases (lifetimes disjoint)
  float* xn2 = x_tok;
  float* t1  = xz2;
  float* t2  = u4;
  float* out = (float*)d_out;

  k_rmsnorm1<<<(BL+255)/256, 256, 0, stream>>>(x, n1w, x_tok, x_norm);

  // in_proj, both orientations: M = 2*BL (rowmode 1 gathers v-order rows for o=1)
  gemm(stream, 128, x_norm, CDIM, 1, in_w[0], in_w[1], nullptr, nullptr, BL,
       xz2, 768, 2*BL, 768, CDIM, 0);
  // depthwise conv, both orientations, both directions in one pass
  k_conv2<<<(2*BL*DIN+255)/256, 256, 0, stream>>>(xz2, conv_w[0], conv_b[0],
                                                  conv_w[1], conv_b[1], u4);
  // xproj over all 4 pipelines: M = 4*BL, N=44
  gemm(stream, 64, u4, DIN, 0, xp_w[0], xp_w[1], nullptr, nullptr, 2*BL,
       xdbl4, XD, 4*BL, XD, DIN, 0);
  // dt projection + softplus (dedicated kernel; K=12 is a terrible GEMM shape)
  k_dt<<<4*BL, 384, 0, stream>>>(xdbl4, dt_w[0], dt_w[1], dt_b[0], dt_b[1], delta4);
  // scan: all 4 pipelines in each pass
  k_scanA<<<4*BATCH*NC, 384, 0, stream>>>(u4, delta4, xdbl4, Alog[0], Alog[1], Pb, Hl);
  k_scanB<<<4*BATCH*DST, 384, 0, stream>>>(Pb, Hl, h0b);
  k_scanC<<<4*BATCH*NC, 384, 0, stream>>>(u4, delta4, xdbl4, h0b, Alog[0], Alog[1],
                                          Dp[0], Dp[1], y4);
  k_yfinal<<<(2*BL*DIN+255)/256, 256, 0, stream>>>(y4, xz2);
  // out_proj, both orientations: M = 2*BL (rowmode 2 reads y4[q=0], y4[q=2])
  gemm(stream, 64, y4, DIN, 2, out_w[0], out_w[1], nullptr, nullptr, BL,
       outc, CDIM, 2*BL, CDIM, DIN, 0);

  k_ctxpart<<<BATCH*49, CDIM, 0, stream>>>(outc, outc + (size_t)BL*CDIM, part);
  k_gate<<<1, 256, 0, stream>>>(part, gw1, gb1, gw2, gb2, gateb);
  k_fuse<<<(BL*CDIM+255)/256, 256, 0, stream>>>(x_tok, outc, outc + (size_t)BL*CDIM, gateb, x2);
  k_rmsnorm2<<<(BL+255)/256, 256, 0, stream>>>(x2, n2w, xn2);
  gemm(stream, 128, xn2, CDIM, 0, mw1, nullptr, mb1, nullptr, 1<<30,
       t1, MLPH, BL, MLPH, CDIM, 1);    // gelu
  gemm(stream, 64, t1, MLPH, 0, mw2, nullptr, mb2, nullptr, 1<<30,
       t2, CDIM, BL, CDIM, MLPH, 0);
  k_final<<<(BL*CDIM+255)/256, 256, 0, stream>>>(x2, t2, out);
}